// Round 4
// baseline (1550.997 us; speedup 1.0000x reference)
//
#include <hip/hip_runtime.h>
#include <hip/hip_bf16.h>

#define NNODES 100000
#define NEDGES 3200000
#define INF 128
#define HID 32

// ---------------- degree histograms ----------------
__global__ void k_deg(const int* __restrict__ src, const int* __restrict__ dst,
                      int* __restrict__ outdeg, int* __restrict__ indeg) {
    int i = blockIdx.x * 256 + threadIdx.x;   // grid = E/256 exact
    atomicAdd(&outdeg[src[i]], 1);
    atomicAdd(&indeg[dst[i]], 1);
}

// ---------------- norms + row offsets ----------------
__global__ void k_norm(const int* __restrict__ outdeg, const int* __restrict__ indeg,
                       float* __restrict__ out_norm, float* __restrict__ in_norm,
                       int* __restrict__ rowstart, int* __restrict__ cursor,
                       int* __restrict__ counter) {
    int n = blockIdx.x * 256 + threadIdx.x;
    if (n < NNODES) {
        int od = outdeg[n], id = indeg[n];
        out_norm[n] = rsqrtf((float)(od > 1 ? od : 1));
        in_norm[n]  = rsqrtf((float)(id > 1 ? id : 1));
        int s = atomicAdd(counter, id);
        rowstart[n] = s;
        cursor[n]   = s;
    }
}

// ---------------- CSR scatter (col = src grouped by dst, arbitrary in-row order) ---
// nontemporal store: skip L2 write-allocate on the random 4B col[] writes. The
// 12.8MB col region merges in the 256MB memory-side Infinity Cache instead of
// thrashing partial 64B lines across 8 non-coherent per-XCD L2s (which showed
// as 200MB WRITE_SIZE = 16x amplification with both plain stores and atomicExch).
__global__ void k_scatter(const int* __restrict__ src, const int* __restrict__ dst,
                          int* __restrict__ cursor, int* __restrict__ col) {
    int i = blockIdx.x * 256 + threadIdx.x;   // grid = E/256 exact
    int d = dst[i];
    int pos = atomicAdd(&cursor[d], 1);
    __builtin_nontemporal_store(src[i], &col[pos]);
}

// ---------------- conv1 dense part: t[n] = out_norm[n] * (x[n] @ W1) ----------------
__global__ void k_gemm1(const float* __restrict__ x, const float* __restrict__ W1,
                        const float* __restrict__ out_norm, float* __restrict__ t) {
    __shared__ float wlds[INF * HID];          // 16 KB
    __shared__ float xlds[8][INF];             // 4 KB
    int tid = threadIdx.x;
    for (int i = tid; i < INF * HID; i += 256) wlds[i] = W1[i];
    int group = tid >> 5, lane = tid & 31;
    int row = blockIdx.x * 8 + group;          // grid = N/8 exact (12500)
    float4 xv = ((const float4*)(x + (size_t)row * INF))[lane];
    ((float4*)xlds[group])[lane] = xv;
    __syncthreads();
    float acc = 0.f;
#pragma unroll
    for (int k = 0; k < INF; ++k)
        acc += xlds[group][k] * wlds[k * HID + lane];
    t[(size_t)row * HID + lane] = acc * out_norm[row];
}

// ---------------- fused SpMM step (round-1 form, known-good) ----------------
// acc = sum_{e in row(n)} gin[col[e]]; acc *= in_norm
// APPLY_W: res = b + acc @ W   else: res = acc + b
// FINAL:   gout = res          else: gout = res * out_norm (pre-scale for next step)
template<int APPLY_W, int FINAL>
__global__ void k_spmm(const float* __restrict__ gin, const int* __restrict__ rowstart,
                       const int* __restrict__ indeg, const int* __restrict__ col,
                       const float* __restrict__ in_norm, const float* __restrict__ out_norm,
                       const float* __restrict__ W, const float* __restrict__ bias,
                       float* __restrict__ gout) {
    __shared__ float wlds[HID * HID];          // 4 KB
    __shared__ float sh[8][HID];
    int tid = threadIdx.x, lane = tid & 31, group = tid >> 5;
    if (APPLY_W) {
        for (int i = tid; i < HID * HID; i += 256) wlds[i] = W[i];
        __syncthreads();
    }
    int n = blockIdx.x * 8 + group;            // grid = N/8 exact
    int start = rowstart[n];
    int deg   = indeg[n];
    float acc = 0.f;
    for (int base = 0; base < deg; base += 32) {
        int c = 0;
        if (base + lane < deg) c = col[start + base + lane];
        int m = deg - base; if (m > 32) m = 32;
        for (int j = 0; j < m; ++j) {
            int s = __shfl(c, j, 32);
            acc += gin[(size_t)s * HID + lane];
        }
    }
    acc *= in_norm[n];
    float res;
    if (APPLY_W) {
        sh[group][lane] = acc;                 // within-wave (32-lane group inside wave64)
        float o = bias[lane];
#pragma unroll
        for (int k = 0; k < HID; ++k)
            o += sh[group][k] * wlds[k * HID + lane];
        res = o;
    } else {
        res = acc + bias[lane];
    }
    if (FINAL) gout[(size_t)n * HID + lane] = res;
    else       gout[(size_t)n * HID + lane] = res * out_norm[n];
}

extern "C" void kernel_launch(void* const* d_in, const int* in_sizes, int n_in,
                              void* d_out, int out_size, void* d_ws, size_t ws_size,
                              hipStream_t stream) {
    const float* in_feat = (const float*)d_in[0];
    const float* W1      = (const float*)d_in[1];
    const float* b1      = (const float*)d_in[2];
    const float* W2      = (const float*)d_in[3];
    const float* b2      = (const float*)d_in[4];
    const int*   src     = (const int*)d_in[5];
    const int*   dst     = (const int*)d_in[6];
    float*       out     = (float*)d_out;

    const int N = NNODES, E = NEDGES;
    // workspace layout (all 4-byte units; every block 16B-aligned)
    int* outdeg   = (int*)d_ws;                 // N
    int* indeg    = outdeg + N;                 // N
    int* counter  = indeg + N;                  // 4 (use [0])
    int* rowstart = counter + 4;                // N
    int* cursor   = rowstart + N;               // N
    float* out_norm = (float*)(cursor + N);     // N
    float* in_norm  = out_norm + N;             // N
    int*   col      = (int*)(in_norm + N);      // E
    float* bufA     = (float*)(col + E);        // N*32
    float* bufB     = bufA + (size_t)N * HID;   // N*32
    size_t need = ((size_t)6 * N + 4 + E + (size_t)2 * N * HID) * 4;
    if (ws_size < need) return;                 // fail visibly rather than corrupt

    // zero outdeg, indeg, counter in one shot (contiguous)
    hipMemsetAsync(outdeg, 0, (size_t)(2 * N + 4) * sizeof(int), stream);

    k_deg    <<<E / 256, 256, 0, stream>>>(src, dst, outdeg, indeg);
    k_norm   <<<(N + 255) / 256, 256, 0, stream>>>(outdeg, indeg, out_norm, in_norm,
                                                   rowstart, cursor, counter);
    k_scatter<<<E / 256, 256, 0, stream>>>(src, dst, cursor, col);

    // conv1 dense projection (weight_first since 128>32)
    k_gemm1<<<N / 8, 256, 0, stream>>>(in_feat, W1, out_norm, bufA);

    // conv1 aggregate: bufA -> bufB, res = agg*in_norm + b1, pre-scaled by out_norm
    k_spmm<0, 0><<<N / 8, 256, 0, stream>>>(bufA, rowstart, indeg, col, in_norm,
                                            out_norm, W2, b1, bufB);

    // 6 middle convs: ping-pong B->A->B->...
    float* cur = bufB; float* nxt = bufA;
    for (int i = 0; i < 6; ++i) {
        k_spmm<1, 0><<<N / 8, 256, 0, stream>>>(cur, rowstart, indeg, col, in_norm,
                                                out_norm, W2, b2, nxt);
        float* tmp = cur; cur = nxt; nxt = tmp;
    }
    // final conv: cur -> out (no out_norm pre-scale, raw h)
    k_spmm<1, 1><<<N / 8, 256, 0, stream>>>(cur, rowstart, indeg, col, in_norm,
                                            out_norm, W2, b2, out);
}

// Round 5
// 1319.327 us; speedup vs baseline: 1.1756x; 1.1756x over previous
//
#include <hip/hip_runtime.h>
#include <hip/hip_bf16.h>

#define NNODES 100000
#define NEDGES 3200000
#define INF 128
#define HID 32
#define NB 49            // buckets: dst>>11, 2048 nodes each (49*2048 = 100352)
#define SCAN_BLOCKS 391  // ceil(N/256)

// ---------------- degree histograms ----------------
__global__ void k_deg(const int* __restrict__ src, const int* __restrict__ dst,
                      int* __restrict__ outdeg, int* __restrict__ indeg) {
    int i = blockIdx.x * 256 + threadIdx.x;   // grid = E/256 exact
    atomicAdd(&outdeg[src[i]], 1);
    atomicAdd(&indeg[dst[i]], 1);
}

// ---------------- norms only ----------------
__global__ void k_norm(const int* __restrict__ outdeg, const int* __restrict__ indeg,
                       float* __restrict__ out_norm, float* __restrict__ in_norm) {
    int n = blockIdx.x * 256 + threadIdx.x;
    if (n < NNODES) {
        int od = outdeg[n], id = indeg[n];
        out_norm[n] = rsqrtf((float)(od > 1 ? od : 1));
        in_norm[n]  = rsqrtf((float)(id > 1 ? id : 1));
    }
}

// ---------------- exclusive scan of indeg -> rowstart (node-ordered CSR) ---------
__global__ void k_scan1(const int* __restrict__ indeg, int* __restrict__ rowstart,
                        int* __restrict__ bsum) {
    __shared__ int s[256];
    int tid = threadIdx.x;
    int i = blockIdx.x * 256 + tid;
    int v = (i < NNODES) ? indeg[i] : 0;
    s[tid] = v;
    __syncthreads();
    for (int off = 1; off < 256; off <<= 1) {
        int t = (tid >= off) ? s[tid - off] : 0;
        __syncthreads();
        s[tid] += t;
        __syncthreads();
    }
    if (i < NNODES) rowstart[i] = s[tid] - v;      // exclusive
    if (tid == 255) bsum[blockIdx.x] = s[255];     // block total
}

__global__ void k_scan2(int* __restrict__ bsum) {   // 1 block, 512 threads
    __shared__ int s[512];
    int tid = threadIdx.x;
    int v = (tid < SCAN_BLOCKS) ? bsum[tid] : 0;
    s[tid] = v;
    __syncthreads();
    for (int off = 1; off < 512; off <<= 1) {
        int t = (tid >= off) ? s[tid - off] : 0;
        __syncthreads();
        s[tid] += t;
        __syncthreads();
    }
    if (tid < SCAN_BLOCKS) bsum[tid] = s[tid] - v; // exclusive
}

__global__ void k_scan3(int* __restrict__ rowstart, const int* __restrict__ bsum) {
    int i = blockIdx.x * 256 + threadIdx.x;
    if (i < NNODES) rowstart[i] += bsum[blockIdx.x];
}

__global__ void k_initcur(const int* __restrict__ rowstart, int* __restrict__ gcursor) {
    int b = threadIdx.x;
    if (b < NB) gcursor[b] = rowstart[b * 2048];
}

// ---------------- pass B: partition edges into bucket-contiguous (dst,src) pairs ---
// Per 2048-edge batch: LDS histogram ranks edges per bucket; one atomicAdd per
// bucket reserves a contiguous chunk (~42 pairs ~340B) -> near-1x write traffic.
__global__ void k_bucket(const int* __restrict__ src, const int* __restrict__ dst,
                         int* __restrict__ gcursor, int2* __restrict__ pairbuf) {
    __shared__ int hist[NB];
    __shared__ int base[NB];
    int tid = threadIdx.x;
    if (tid < NB) hist[tid] = 0;
    __syncthreads();
    int start = blockIdx.x * 2048;
    int myb[8], myr[8]; int2 mye[8];
#pragma unroll
    for (int k = 0; k < 8; ++k) {
        int i = start + tid + k * 256;
        myb[k] = -1;
        if (i < NEDGES) {
            int d = dst[i], s = src[i];
            int b = d >> 11;
            myr[k] = atomicAdd(&hist[b], 1);
            myb[k] = b;
            mye[k].x = d; mye[k].y = s;
        }
    }
    __syncthreads();
    if (tid < NB && hist[tid] > 0) base[tid] = atomicAdd(&gcursor[tid], hist[tid]);
    __syncthreads();
#pragma unroll
    for (int k = 0; k < 8; ++k)
        if (myb[k] >= 0) pairbuf[base[myb[k]] + myr[k]] = mye[k];
}

// ---------------- pass C: within-bucket placement; col window is XCD-L2-local ----
__global__ void k_place(const int2* __restrict__ pairbuf, const int* __restrict__ rowstart,
                        int* __restrict__ col) {
    __shared__ int cur[2048];
    int tid = threadIdx.x;
    int bucket = blockIdx.x;
    int node0 = bucket * 2048;
    for (int j = tid; j < 2048; j += 256) {
        int n = node0 + j;
        cur[j] = (n < NNODES) ? rowstart[n] : 0;
    }
    __syncthreads();
    int pstart = rowstart[node0];
    int pend   = (bucket == NB - 1) ? NEDGES : rowstart[node0 + 2048];
    for (int i = pstart + tid; i < pend; i += 256) {
        int2 e = pairbuf[i];
        int pos = atomicAdd(&cur[e.x - node0], 1);
        col[pos] = e.y;
    }
}

// ---------------- conv1 dense part: t[n] = out_norm[n] * (x[n] @ W1) ----------------
__global__ void k_gemm1(const float* __restrict__ x, const float* __restrict__ W1,
                        const float* __restrict__ out_norm, float* __restrict__ t) {
    __shared__ float wlds[INF * HID];          // 16 KB
    __shared__ float xlds[8][INF];             // 4 KB
    int tid = threadIdx.x;
    for (int i = tid; i < INF * HID; i += 256) wlds[i] = W1[i];
    int group = tid >> 5, lane = tid & 31;
    int row = blockIdx.x * 8 + group;          // grid = N/8 exact (12500)
    float4 xv = ((const float4*)(x + (size_t)row * INF))[lane];
    ((float4*)xlds[group])[lane] = xv;
    __syncthreads();
    float acc = 0.f;
#pragma unroll
    for (int k = 0; k < INF; ++k)
        acc += xlds[group][k] * wlds[k * HID + lane];
    t[(size_t)row * HID + lane] = acc * out_norm[row];
}

// ---------------- fused SpMM step (round-1 form, known-good) ----------------
template<int APPLY_W, int FINAL>
__global__ void k_spmm(const float* __restrict__ gin, const int* __restrict__ rowstart,
                       const int* __restrict__ indeg, const int* __restrict__ col,
                       const float* __restrict__ in_norm, const float* __restrict__ out_norm,
                       const float* __restrict__ W, const float* __restrict__ bias,
                       float* __restrict__ gout) {
    __shared__ float wlds[HID * HID];          // 4 KB
    __shared__ float sh[8][HID];
    int tid = threadIdx.x, lane = tid & 31, group = tid >> 5;
    if (APPLY_W) {
        for (int i = tid; i < HID * HID; i += 256) wlds[i] = W[i];
        __syncthreads();
    }
    int n = blockIdx.x * 8 + group;            // grid = N/8 exact
    int start = rowstart[n];
    int deg   = indeg[n];
    float acc = 0.f;
    for (int base = 0; base < deg; base += 32) {
        int c = 0;
        if (base + lane < deg) c = col[start + base + lane];
        int m = deg - base; if (m > 32) m = 32;
        for (int j = 0; j < m; ++j) {
            int s = __shfl(c, j, 32);
            acc += gin[(size_t)s * HID + lane];
        }
    }
    acc *= in_norm[n];
    float res;
    if (APPLY_W) {
        sh[group][lane] = acc;
        float o = bias[lane];
#pragma unroll
        for (int k = 0; k < HID; ++k)
            o += sh[group][k] * wlds[k * HID + lane];
        res = o;
    } else {
        res = acc + bias[lane];
    }
    if (FINAL) gout[(size_t)n * HID + lane] = res;
    else       gout[(size_t)n * HID + lane] = res * out_norm[n];
}

extern "C" void kernel_launch(void* const* d_in, const int* in_sizes, int n_in,
                              void* d_out, int out_size, void* d_ws, size_t ws_size,
                              hipStream_t stream) {
    const float* in_feat = (const float*)d_in[0];
    const float* W1      = (const float*)d_in[1];
    const float* b1      = (const float*)d_in[2];
    const float* W2      = (const float*)d_in[3];
    const float* b2      = (const float*)d_in[4];
    const int*   src     = (const int*)d_in[5];
    const int*   dst     = (const int*)d_in[6];
    float*       out     = (float*)d_out;

    const int N = NNODES, E = NEDGES;
    // workspace layout (4-byte units)
    int* outdeg   = (int*)d_ws;                 // N
    int* indeg    = outdeg + N;                 // N
    int* rowstart = indeg + N;                  // N
    int* bsum     = rowstart + N;               // 512
    int* gcursor  = bsum + 512;                 // 64
    float* out_norm = (float*)(gcursor + 64);   // N
    float* in_norm  = out_norm + N;             // N
    int*   col      = (int*)(in_norm + N);      // E
    float* bufA     = (float*)(col + E);        // N*32  (aliased by pairbuf pre-gemm)
    float* bufB     = bufA + (size_t)N * HID;   // N*32
    int2*  pairbuf  = (int2*)bufA;              // E pairs = 2*N*32 ints exactly fits A+B
    size_t need = ((size_t)5 * N + 576 + E + (size_t)2 * N * HID) * 4;
    if (ws_size < need) return;                 // fail visibly rather than corrupt

    hipMemsetAsync(outdeg, 0, (size_t)(2 * N) * sizeof(int), stream);

    k_deg    <<<E / 256, 256, 0, stream>>>(src, dst, outdeg, indeg);
    k_norm   <<<SCAN_BLOCKS, 256, 0, stream>>>(outdeg, indeg, out_norm, in_norm);
    k_scan1  <<<SCAN_BLOCKS, 256, 0, stream>>>(indeg, rowstart, bsum);
    k_scan2  <<<1, 512, 0, stream>>>(bsum);
    k_scan3  <<<SCAN_BLOCKS, 256, 0, stream>>>(rowstart, bsum);
    k_initcur<<<1, 64, 0, stream>>>(rowstart, gcursor);
    k_bucket <<<(E + 2047) / 2048, 256, 0, stream>>>(src, dst, gcursor, pairbuf);
    k_place  <<<NB, 256, 0, stream>>>(pairbuf, rowstart, col);

    // conv1 dense projection (weight_first since 128>32)
    k_gemm1<<<N / 8, 256, 0, stream>>>(in_feat, W1, out_norm, bufA);

    // conv1 aggregate: bufA -> bufB, res = agg*in_norm + b1, pre-scaled by out_norm
    k_spmm<0, 0><<<N / 8, 256, 0, stream>>>(bufA, rowstart, indeg, col, in_norm,
                                            out_norm, W2, b1, bufB);

    // 6 middle convs: ping-pong B->A->B->...
    float* cur = bufB; float* nxt = bufA;
    for (int i = 0; i < 6; ++i) {
        k_spmm<1, 0><<<N / 8, 256, 0, stream>>>(cur, rowstart, indeg, col, in_norm,
                                                out_norm, W2, b2, nxt);
        float* tmp = cur; cur = nxt; nxt = tmp;
    }
    // final conv: cur -> out (no out_norm pre-scale, raw h)
    k_spmm<1, 1><<<N / 8, 256, 0, stream>>>(cur, rowstart, indeg, col, in_norm,
                                            out_norm, W2, b2, out);
}

// Round 6
// 1122.432 us; speedup vs baseline: 1.3818x; 1.1754x over previous
//
#include <hip/hip_runtime.h>
#include <hip/hip_bf16.h>

#define NNODES 100000
#define NEDGES 3200000
#define INF 128
#define HID 32
#define NB 49                                  // buckets: node>>11, 2048 nodes each
#define CNT_BLOCKS ((NEDGES + 2047) / 2048)    // 1563

// ---- pass 1: per-block LDS bucket histograms -> global bucket counts (98 atomics/blk)
__global__ void k_cnt(const int* __restrict__ src, const int* __restrict__ dst,
                      int* __restrict__ bcnt_src, int* __restrict__ bcnt_dst) {
    __shared__ int hs[NB], hd[NB];
    int tid = threadIdx.x;
    if (tid < NB) { hs[tid] = 0; hd[tid] = 0; }
    __syncthreads();
    int start = blockIdx.x * 2048;
#pragma unroll
    for (int k = 0; k < 8; ++k) {
        int i = start + tid + k * 256;
        if (i < NEDGES) {
            atomicAdd(&hs[src[i] >> 11], 1);
            atomicAdd(&hd[dst[i] >> 11], 1);
        }
    }
    __syncthreads();
    if (tid < NB) {
        if (hs[tid]) atomicAdd(&bcnt_src[tid], hs[tid]);
        if (hd[tid]) atomicAdd(&bcnt_dst[tid], hd[tid]);
    }
}

// ---- pass 2: exclusive scan of the 49-entry bucket counts (both sides) ----
__global__ void k_bscan(const int* __restrict__ bcnt_src, const int* __restrict__ bcnt_dst,
                        int* __restrict__ bbase_src, int* __restrict__ bbase_dst,
                        int* __restrict__ gcur_src, int* __restrict__ gcur_dst) {
    __shared__ int s[64], t[64];
    int tid = threadIdx.x;
    int vs = (tid < NB) ? bcnt_src[tid] : 0;
    int vd = (tid < NB) ? bcnt_dst[tid] : 0;
    s[tid] = vs; t[tid] = vd;
    __syncthreads();
    for (int off = 1; off < 64; off <<= 1) {
        int a = (tid >= off) ? s[tid - off] : 0;
        int b = (tid >= off) ? t[tid - off] : 0;
        __syncthreads();
        s[tid] += a; t[tid] += b;
        __syncthreads();
    }
    if (tid < NB) {
        bbase_src[tid] = s[tid] - vs;  gcur_src[tid] = s[tid] - vs;
        bbase_dst[tid] = t[tid] - vd;  gcur_dst[tid] = t[tid] - vd;
    }
}

// ---- pass 3: partition edges: (dst,src) pairs by dst-bucket, src vals by src-bucket
__global__ void k_bucket2(const int* __restrict__ src, const int* __restrict__ dst,
                          int* __restrict__ gcur_src, int* __restrict__ gcur_dst,
                          int2* __restrict__ pairbuf, int* __restrict__ srctmp) {
    __shared__ int hs[NB], hd[NB], bs[NB], bd[NB];
    int tid = threadIdx.x;
    if (tid < NB) { hs[tid] = 0; hd[tid] = 0; }
    __syncthreads();
    int start = blockIdx.x * 2048;
    int d8[8], s8[8], rs8[8], rd8[8];
#pragma unroll
    for (int k = 0; k < 8; ++k) {
        int i = start + tid + k * 256;
        d8[k] = -1;
        if (i < NEDGES) {
            int d = dst[i], s = src[i];
            d8[k] = d; s8[k] = s;
            rd8[k] = atomicAdd(&hd[d >> 11], 1);
            rs8[k] = atomicAdd(&hs[s >> 11], 1);
        }
    }
    __syncthreads();
    if (tid < NB) {
        bs[tid] = hs[tid] ? atomicAdd(&gcur_src[tid], hs[tid]) : 0;
        bd[tid] = hd[tid] ? atomicAdd(&gcur_dst[tid], hd[tid]) : 0;
    }
    __syncthreads();
#pragma unroll
    for (int k = 0; k < 8; ++k) {
        if (d8[k] >= 0) {
            int2 e; e.x = d8[k]; e.y = s8[k];
            pairbuf[bd[d8[k] >> 11] + rd8[k]] = e;
            srctmp[bs[s8[k] >> 11] + rs8[k]] = s8[k];
        }
    }
}

// ---- pass 4: per-bucket node stats. b<NB: src-phase (out_norm); else dst-phase
//      (indeg, in_norm, rowstart via in-block scan). No global random atomics.
__global__ void k_nodes(const int* __restrict__ srctmp, const int2* __restrict__ pairbuf,
                        const int* __restrict__ bbase_src, const int* __restrict__ bcnt_src,
                        const int* __restrict__ bbase_dst, const int* __restrict__ bcnt_dst,
                        float* __restrict__ out_norm, float* __restrict__ in_norm,
                        int* __restrict__ indeg, int* __restrict__ rowstart) {
    __shared__ int cnt[2048];
    __shared__ int ss[1024];
    int tid = threadIdx.x;
    int b = blockIdx.x;
    int srcphase = (b < NB);
    int bb = srcphase ? b : b - NB;
    int node0 = bb * 2048;
    cnt[tid] = 0; cnt[tid + 1024] = 0;
    __syncthreads();
    if (srcphase) {
        int s0 = bbase_src[bb], n = bcnt_src[bb];
        for (int i = tid; i < n; i += 1024)
            atomicAdd(&cnt[srctmp[s0 + i] - node0], 1);
        __syncthreads();
#pragma unroll
        for (int k = 0; k < 2; ++k) {
            int j = tid + k * 1024;
            int nn = node0 + j;
            if (nn < NNODES) {
                int c = cnt[j];
                out_norm[nn] = rsqrtf((float)(c > 1 ? c : 1));
            }
        }
    } else {
        int d0 = bbase_dst[bb], n = bcnt_dst[bb];
        for (int i = tid; i < n; i += 1024)
            atomicAdd(&cnt[pairbuf[d0 + i].x - node0], 1);
        __syncthreads();
        int c0 = cnt[2 * tid], c1 = cnt[2 * tid + 1];
        ss[tid] = c0 + c1;
        __syncthreads();
        for (int off = 1; off < 1024; off <<= 1) {
            int t = (tid >= off) ? ss[tid - off] : 0;
            __syncthreads();
            ss[tid] += t;
            __syncthreads();
        }
        int excl = ss[tid] - (c0 + c1);          // exclusive prefix of node 2*tid
        int n0 = node0 + 2 * tid, n1 = n0 + 1;
        if (n0 < NNODES) {
            indeg[n0] = c0;
            in_norm[n0] = rsqrtf((float)(c0 > 1 ? c0 : 1));
            rowstart[n0] = d0 + excl;
        }
        if (n1 < NNODES) {
            indeg[n1] = c1;
            in_norm[n1] = rsqrtf((float)(c1 > 1 ? c1 : 1));
            rowstart[n1] = d0 + excl + c0;
        }
    }
}

// ---- pass 5: within-bucket placement; col window is one bucket (~260KB), L2-local --
__global__ void k_place(const int2* __restrict__ pairbuf, const int* __restrict__ rowstart,
                        int* __restrict__ col) {
    __shared__ int cur[2048];
    int tid = threadIdx.x;
    int bucket = blockIdx.x;
    int node0 = bucket * 2048;
    for (int j = tid; j < 2048; j += 1024) {
        int n = node0 + j;
        cur[j] = (n < NNODES) ? rowstart[n] : 0;
    }
    __syncthreads();
    int pstart = rowstart[node0];
    int pend   = (bucket == NB - 1) ? NEDGES : rowstart[node0 + 2048];
    for (int i = pstart + tid; i < pend; i += 1024) {
        int2 e = pairbuf[i];
        int pos = atomicAdd(&cur[e.x - node0], 1);
        col[pos] = e.y;
    }
}

// ---------------- conv1 dense part: t[n] = out_norm[n] * (x[n] @ W1) ----------------
__global__ void k_gemm1(const float* __restrict__ x, const float* __restrict__ W1,
                        const float* __restrict__ out_norm, float* __restrict__ t) {
    __shared__ float wlds[INF * HID];          // 16 KB
    __shared__ float xlds[8][INF];             // 4 KB
    int tid = threadIdx.x;
    for (int i = tid; i < INF * HID; i += 256) wlds[i] = W1[i];
    int group = tid >> 5, lane = tid & 31;
    int row = blockIdx.x * 8 + group;          // grid = N/8 exact (12500)
    float4 xv = ((const float4*)(x + (size_t)row * INF))[lane];
    ((float4*)xlds[group])[lane] = xv;
    __syncthreads();
    float acc = 0.f;
#pragma unroll
    for (int k = 0; k < INF; ++k)
        acc += xlds[group][k] * wlds[k * HID + lane];
    t[(size_t)row * HID + lane] = acc * out_norm[row];
}

// ---------------- fused SpMM step (round-1 form, known-good, untouched) ------------
template<int APPLY_W, int FINAL>
__global__ void k_spmm(const float* __restrict__ gin, const int* __restrict__ rowstart,
                       const int* __restrict__ indeg, const int* __restrict__ col,
                       const float* __restrict__ in_norm, const float* __restrict__ out_norm,
                       const float* __restrict__ W, const float* __restrict__ bias,
                       float* __restrict__ gout) {
    __shared__ float wlds[HID * HID];          // 4 KB
    __shared__ float sh[8][HID];
    int tid = threadIdx.x, lane = tid & 31, group = tid >> 5;
    if (APPLY_W) {
        for (int i = tid; i < HID * HID; i += 256) wlds[i] = W[i];
        __syncthreads();
    }
    int n = blockIdx.x * 8 + group;            // grid = N/8 exact
    int start = rowstart[n];
    int deg   = indeg[n];
    float acc = 0.f;
    for (int base = 0; base < deg; base += 32) {
        int c = 0;
        if (base + lane < deg) c = col[start + base + lane];
        int m = deg - base; if (m > 32) m = 32;
        for (int j = 0; j < m; ++j) {
            int s = __shfl(c, j, 32);
            acc += gin[(size_t)s * HID + lane];
        }
    }
    acc *= in_norm[n];
    float res;
    if (APPLY_W) {
        sh[group][lane] = acc;
        float o = bias[lane];
#pragma unroll
        for (int k = 0; k < HID; ++k)
            o += sh[group][k] * wlds[k * HID + lane];
        res = o;
    } else {
        res = acc + bias[lane];
    }
    if (FINAL) gout[(size_t)n * HID + lane] = res;
    else       gout[(size_t)n * HID + lane] = res * out_norm[n];
}

extern "C" void kernel_launch(void* const* d_in, const int* in_sizes, int n_in,
                              void* d_out, int out_size, void* d_ws, size_t ws_size,
                              hipStream_t stream) {
    const float* in_feat = (const float*)d_in[0];
    const float* W1      = (const float*)d_in[1];
    const float* b1      = (const float*)d_in[2];
    const float* W2      = (const float*)d_in[3];
    const float* b2      = (const float*)d_in[4];
    const int*   src     = (const int*)d_in[5];
    const int*   dst     = (const int*)d_in[6];
    float*       out     = (float*)d_out;

    const int N = NNODES, E = NEDGES;
    // workspace layout (4-byte units)
    int* bcnt_src  = (int*)d_ws;                // 64
    int* bcnt_dst  = bcnt_src + 64;             // 64
    int* bbase_src = bcnt_dst + 64;             // 64
    int* bbase_dst = bbase_src + 64;            // 64
    int* gcur_src  = bbase_dst + 64;            // 64
    int* gcur_dst  = gcur_src + 64;             // 64
    int* indeg     = gcur_dst + 64;             // N
    int* rowstart  = indeg + N;                 // N
    float* out_norm = (float*)(rowstart + N);   // N
    float* in_norm  = out_norm + N;             // N
    int*   col      = (int*)(in_norm + N);      // E   (aliased as srctmp pre-place)
    float* bufA     = (float*)(col + E);        // N*HID (aliased by pairbuf pre-gemm)
    float* bufB     = bufA + (size_t)N * HID;   // N*HID
    int2*  pairbuf  = (int2*)bufA;              // E pairs = exactly bufA+bufB
    int*   srctmp   = col;                      // E ints, consumed before col written
    size_t need = ((size_t)384 + 4 * N + E + (size_t)2 * N * HID) * 4;
    if (ws_size < need) return;                 // fail visibly rather than corrupt

    hipMemsetAsync(bcnt_src, 0, 128 * sizeof(int), stream);  // bcnt_src + bcnt_dst

    k_cnt    <<<CNT_BLOCKS, 256, 0, stream>>>(src, dst, bcnt_src, bcnt_dst);
    k_bscan  <<<1, 64, 0, stream>>>(bcnt_src, bcnt_dst, bbase_src, bbase_dst,
                                    gcur_src, gcur_dst);
    k_bucket2<<<CNT_BLOCKS, 256, 0, stream>>>(src, dst, gcur_src, gcur_dst,
                                              pairbuf, srctmp);
    k_nodes  <<<2 * NB, 1024, 0, stream>>>(srctmp, pairbuf, bbase_src, bcnt_src,
                                           bbase_dst, bcnt_dst, out_norm, in_norm,
                                           indeg, rowstart);
    k_place  <<<NB, 1024, 0, stream>>>(pairbuf, rowstart, col);

    // conv1 dense projection (weight_first since 128>32)
    k_gemm1<<<N / 8, 256, 0, stream>>>(in_feat, W1, out_norm, bufA);

    // conv1 aggregate: bufA -> bufB, res = agg*in_norm + b1, pre-scaled by out_norm
    k_spmm<0, 0><<<N / 8, 256, 0, stream>>>(bufA, rowstart, indeg, col, in_norm,
                                            out_norm, W2, b1, bufB);

    // 6 middle convs: ping-pong B->A->B->...
    float* cur = bufB; float* nxt = bufA;
    for (int i = 0; i < 6; ++i) {
        k_spmm<1, 0><<<N / 8, 256, 0, stream>>>(cur, rowstart, indeg, col, in_norm,
                                                out_norm, W2, b2, nxt);
        float* tmp = cur; cur = nxt; nxt = tmp;
    }
    // final conv: cur -> out (no out_norm pre-scale, raw h)
    k_spmm<1, 1><<<N / 8, 256, 0, stream>>>(cur, rowstart, indeg, col, in_norm,
                                            out_norm, W2, b2, out);
}

// Round 7
// 699.267 us; speedup vs baseline: 2.2180x; 1.6052x over previous
//
#include <hip/hip_runtime.h>
#include <hip/hip_bf16.h>

#define NNODES 100000
#define NEDGES 3200000
#define INF 128
#define HID 32
#define NB 49                                  // buckets: node>>11, 2048 nodes each
#define CNT_BLOCKS ((NEDGES + 2047) / 2048)    // 1563

// ---- pass 1: per-block LDS bucket histograms -> global bucket counts (98 atomics/blk)
__global__ void k_cnt(const int* __restrict__ src, const int* __restrict__ dst,
                      int* __restrict__ bcnt_src, int* __restrict__ bcnt_dst) {
    __shared__ int hs[NB], hd[NB];
    int tid = threadIdx.x;
    if (tid < NB) { hs[tid] = 0; hd[tid] = 0; }
    __syncthreads();
    int start = blockIdx.x * 2048;
#pragma unroll
    for (int k = 0; k < 8; ++k) {
        int i = start + tid + k * 256;
        if (i < NEDGES) {
            atomicAdd(&hs[src[i] >> 11], 1);
            atomicAdd(&hd[dst[i] >> 11], 1);
        }
    }
    __syncthreads();
    if (tid < NB) {
        if (hs[tid]) atomicAdd(&bcnt_src[tid], hs[tid]);
        if (hd[tid]) atomicAdd(&bcnt_dst[tid], hd[tid]);
    }
}

// ---- pass 2: exclusive scan of the 49-entry bucket counts (both sides) ----
__global__ void k_bscan(const int* __restrict__ bcnt_src, const int* __restrict__ bcnt_dst,
                        int* __restrict__ bbase_src, int* __restrict__ bbase_dst,
                        int* __restrict__ gcur_src, int* __restrict__ gcur_dst) {
    __shared__ int s[64], t[64];
    int tid = threadIdx.x;
    int vs = (tid < NB) ? bcnt_src[tid] : 0;
    int vd = (tid < NB) ? bcnt_dst[tid] : 0;
    s[tid] = vs; t[tid] = vd;
    __syncthreads();
    for (int off = 1; off < 64; off <<= 1) {
        int a = (tid >= off) ? s[tid - off] : 0;
        int b = (tid >= off) ? t[tid - off] : 0;
        __syncthreads();
        s[tid] += a; t[tid] += b;
        __syncthreads();
    }
    if (tid < NB) {
        bbase_src[tid] = s[tid] - vs;  gcur_src[tid] = s[tid] - vs;
        bbase_dst[tid] = t[tid] - vd;  gcur_dst[tid] = t[tid] - vd;
    }
}

// ---- pass 3: partition edges: (dst,src) pairs by dst-bucket, src vals by src-bucket
__global__ void k_bucket2(const int* __restrict__ src, const int* __restrict__ dst,
                          int* __restrict__ gcur_src, int* __restrict__ gcur_dst,
                          int2* __restrict__ pairbuf, int* __restrict__ srctmp) {
    __shared__ int hs[NB], hd[NB], bs[NB], bd[NB];
    int tid = threadIdx.x;
    if (tid < NB) { hs[tid] = 0; hd[tid] = 0; }
    __syncthreads();
    int start = blockIdx.x * 2048;
    int d8[8], s8[8], rs8[8], rd8[8];
#pragma unroll
    for (int k = 0; k < 8; ++k) {
        int i = start + tid + k * 256;
        d8[k] = -1;
        if (i < NEDGES) {
            int d = dst[i], s = src[i];
            d8[k] = d; s8[k] = s;
            rd8[k] = atomicAdd(&hd[d >> 11], 1);
            rs8[k] = atomicAdd(&hs[s >> 11], 1);
        }
    }
    __syncthreads();
    if (tid < NB) {
        bs[tid] = hs[tid] ? atomicAdd(&gcur_src[tid], hs[tid]) : 0;
        bd[tid] = hd[tid] ? atomicAdd(&gcur_dst[tid], hd[tid]) : 0;
    }
    __syncthreads();
#pragma unroll
    for (int k = 0; k < 8; ++k) {
        if (d8[k] >= 0) {
            int2 e; e.x = d8[k]; e.y = s8[k];
            pairbuf[bd[d8[k] >> 11] + rd8[k]] = e;
            srctmp[bs[s8[k] >> 11] + rs8[k]] = s8[k];
        }
    }
}

// ---- pass 4: per-bucket node stats. b<NB: src-phase (out_norm); else dst-phase
__global__ void k_nodes(const int* __restrict__ srctmp, const int2* __restrict__ pairbuf,
                        const int* __restrict__ bbase_src, const int* __restrict__ bcnt_src,
                        const int* __restrict__ bbase_dst, const int* __restrict__ bcnt_dst,
                        float* __restrict__ out_norm, float* __restrict__ in_norm,
                        int* __restrict__ indeg, int* __restrict__ rowstart) {
    __shared__ int cnt[2048];
    __shared__ int ss[1024];
    int tid = threadIdx.x;
    int b = blockIdx.x;
    int srcphase = (b < NB);
    int bb = srcphase ? b : b - NB;
    int node0 = bb * 2048;
    cnt[tid] = 0; cnt[tid + 1024] = 0;
    __syncthreads();
    if (srcphase) {
        int s0 = bbase_src[bb], n = bcnt_src[bb];
        for (int i = tid; i < n; i += 1024)
            atomicAdd(&cnt[srctmp[s0 + i] - node0], 1);
        __syncthreads();
#pragma unroll
        for (int k = 0; k < 2; ++k) {
            int j = tid + k * 1024;
            int nn = node0 + j;
            if (nn < NNODES) {
                int c = cnt[j];
                out_norm[nn] = rsqrtf((float)(c > 1 ? c : 1));
            }
        }
    } else {
        int d0 = bbase_dst[bb], n = bcnt_dst[bb];
        for (int i = tid; i < n; i += 1024)
            atomicAdd(&cnt[pairbuf[d0 + i].x - node0], 1);
        __syncthreads();
        int c0 = cnt[2 * tid], c1 = cnt[2 * tid + 1];
        ss[tid] = c0 + c1;
        __syncthreads();
        for (int off = 1; off < 1024; off <<= 1) {
            int t = (tid >= off) ? ss[tid - off] : 0;
            __syncthreads();
            ss[tid] += t;
            __syncthreads();
        }
        int excl = ss[tid] - (c0 + c1);
        int n0 = node0 + 2 * tid, n1 = n0 + 1;
        if (n0 < NNODES) {
            indeg[n0] = c0;
            in_norm[n0] = rsqrtf((float)(c0 > 1 ? c0 : 1));
            rowstart[n0] = d0 + excl;
        }
        if (n1 < NNODES) {
            indeg[n1] = c1;
            in_norm[n1] = rsqrtf((float)(c1 > 1 ? c1 : 1));
            rowstart[n1] = d0 + excl + c0;
        }
    }
}

// ---- pass 5: within-bucket placement; col window is one bucket (~260KB), L2-local --
__global__ void k_place(const int2* __restrict__ pairbuf, const int* __restrict__ rowstart,
                        int* __restrict__ col) {
    __shared__ int cur[2048];
    int tid = threadIdx.x;
    int bucket = blockIdx.x;
    int node0 = bucket * 2048;
    for (int j = tid; j < 2048; j += 1024) {
        int n = node0 + j;
        cur[j] = (n < NNODES) ? rowstart[n] : 0;
    }
    __syncthreads();
    int pstart = rowstart[node0];
    int pend   = (bucket == NB - 1) ? NEDGES : rowstart[node0 + 2048];
    for (int i = pstart + tid; i < pend; i += 1024) {
        int2 e = pairbuf[i];
        int pos = atomicAdd(&cur[e.x - node0], 1);
        col[pos] = e.y;
    }
}

// ---------------- conv1 dense part: t[n] = out_norm[n] * (x[n] @ W1) ----------------
__global__ void k_gemm1(const float* __restrict__ x, const float* __restrict__ W1,
                        const float* __restrict__ out_norm, float* __restrict__ t) {
    __shared__ float wlds[INF * HID];          // 16 KB
    __shared__ float xlds[8][INF];             // 4 KB
    int tid = threadIdx.x;
    for (int i = tid; i < INF * HID; i += 256) wlds[i] = W1[i];
    int group = tid >> 5, lane = tid & 31;
    int row = blockIdx.x * 8 + group;          // grid = N/8 exact (12500)
    float4 xv = ((const float4*)(x + (size_t)row * INF))[lane];
    ((float4*)xlds[group])[lane] = xv;
    __syncthreads();
    float acc = 0.f;
#pragma unroll
    for (int k = 0; k < INF; ++k)
        acc += xlds[group][k] * wlds[k * HID + lane];
    t[(size_t)row * HID + lane] = acc * out_norm[row];
}

// ---------------- fused SpMM step — float4 gather, 4 edges/step, 8 loads in flight --
// 32-lane group per node; subgroup g=lane>>3 (4 edges in parallel), f=lane&7
// (feature quad). Each quad-step: 1 bpermute + 1 global_load_dwordx4 + 4 adds
// covers 4 edges. Full 32-edge chunks are branch-free with 8 independent loads.
template<int APPLY_W, int FINAL>
__global__ void k_spmm(const float* __restrict__ gin, const int* __restrict__ rowstart,
                       const int* __restrict__ indeg, const int* __restrict__ col,
                       const float* __restrict__ in_norm, const float* __restrict__ out_norm,
                       const float* __restrict__ W, const float* __restrict__ bias,
                       float* __restrict__ gout) {
    __shared__ float wlds[HID * HID];          // 4 KB
    __shared__ float sh[8][HID];
    int tid = threadIdx.x, lane = tid & 31, group = tid >> 5;
    int g = lane >> 3, f = lane & 7;
    if (APPLY_W) {
        for (int i = tid; i < HID * HID; i += 256) wlds[i] = W[i];
        __syncthreads();
    }
    int n = blockIdx.x * 8 + group;            // grid = N/8 exact
    int start = rowstart[n];
    int deg   = indeg[n];
    const float4* gin4 = (const float4*)gin;

    float4 acc = make_float4(0.f, 0.f, 0.f, 0.f);
    int base = 0;
    for (; base + 32 <= deg; base += 32) {     // full chunks: no predication
        int c = col[start + base + lane];
#pragma unroll
        for (int t = 0; t < 8; ++t) {
            int s = __shfl(c, t * 4 + g, 32);
            float4 v = gin4[(size_t)s * 8 + f];
            acc.x += v.x; acc.y += v.y; acc.z += v.z; acc.w += v.w;
        }
    }
    if (base < deg) {                          // tail chunk (rem in 1..31)
        int rem = deg - base;
        int c = (base + lane < deg) ? col[start + base + lane] : 0;
#pragma unroll
        for (int t = 0; t < 8; ++t) {
            if (t * 4 < rem) {
                int e = t * 4 + g;
                int s = __shfl(c, e, 32);
                float4 v = gin4[(size_t)s * 8 + f];
                float m = (e < rem) ? 1.f : 0.f;
                acc.x = fmaf(m, v.x, acc.x);
                acc.y = fmaf(m, v.y, acc.y);
                acc.z = fmaf(m, v.z, acc.z);
                acc.w = fmaf(m, v.w, acc.w);
            }
        }
    }
    // reduce the 4 edge-subgroups (lane bits 3,4)
    acc.x += __shfl_xor(acc.x, 8, 32);  acc.y += __shfl_xor(acc.y, 8, 32);
    acc.z += __shfl_xor(acc.z, 8, 32);  acc.w += __shfl_xor(acc.w, 8, 32);
    acc.x += __shfl_xor(acc.x, 16, 32); acc.y += __shfl_xor(acc.y, 16, 32);
    acc.z += __shfl_xor(acc.z, 16, 32); acc.w += __shfl_xor(acc.w, 16, 32);

    float inm = in_norm[n];
    acc.x *= inm; acc.y *= inm; acc.z *= inm; acc.w *= inm;
    if (g == 0) *(float4*)&sh[group][4 * f] = acc;   // same-wave LDS fill

    float res;
    if (APPLY_W) {
        float o = bias[lane];
#pragma unroll
        for (int k = 0; k < HID; ++k)
            o += sh[group][k] * wlds[k * HID + lane];
        res = o;
    } else {
        res = sh[group][lane] + bias[lane];
    }
    if (FINAL) gout[(size_t)n * HID + lane] = res;
    else       gout[(size_t)n * HID + lane] = res * out_norm[n];
}

extern "C" void kernel_launch(void* const* d_in, const int* in_sizes, int n_in,
                              void* d_out, int out_size, void* d_ws, size_t ws_size,
                              hipStream_t stream) {
    const float* in_feat = (const float*)d_in[0];
    const float* W1      = (const float*)d_in[1];
    const float* b1      = (const float*)d_in[2];
    const float* W2      = (const float*)d_in[3];
    const float* b2      = (const float*)d_in[4];
    const int*   src     = (const int*)d_in[5];
    const int*   dst     = (const int*)d_in[6];
    float*       out     = (float*)d_out;

    const int N = NNODES, E = NEDGES;
    // workspace layout (4-byte units)
    int* bcnt_src  = (int*)d_ws;                // 64
    int* bcnt_dst  = bcnt_src + 64;             // 64
    int* bbase_src = bcnt_dst + 64;             // 64
    int* bbase_dst = bbase_src + 64;            // 64
    int* gcur_src  = bbase_dst + 64;            // 64
    int* gcur_dst  = gcur_src + 64;             // 64
    int* indeg     = gcur_dst + 64;             // N
    int* rowstart  = indeg + N;                 // N
    float* out_norm = (float*)(rowstart + N);   // N
    float* in_norm  = out_norm + N;             // N
    int*   col      = (int*)(in_norm + N);      // E   (aliased as srctmp pre-place)
    float* bufA     = (float*)(col + E);        // N*HID (aliased by pairbuf pre-gemm)
    float* bufB     = bufA + (size_t)N * HID;   // N*HID
    int2*  pairbuf  = (int2*)bufA;              // E pairs = exactly bufA+bufB
    int*   srctmp   = col;                      // E ints, consumed before col written
    size_t need = ((size_t)384 + 4 * N + E + (size_t)2 * N * HID) * 4;
    if (ws_size < need) return;                 // fail visibly rather than corrupt

    hipMemsetAsync(bcnt_src, 0, 128 * sizeof(int), stream);  // bcnt_src + bcnt_dst

    k_cnt    <<<CNT_BLOCKS, 256, 0, stream>>>(src, dst, bcnt_src, bcnt_dst);
    k_bscan  <<<1, 64, 0, stream>>>(bcnt_src, bcnt_dst, bbase_src, bbase_dst,
                                    gcur_src, gcur_dst);
    k_bucket2<<<CNT_BLOCKS, 256, 0, stream>>>(src, dst, gcur_src, gcur_dst,
                                              pairbuf, srctmp);
    k_nodes  <<<2 * NB, 1024, 0, stream>>>(srctmp, pairbuf, bbase_src, bcnt_src,
                                           bbase_dst, bcnt_dst, out_norm, in_norm,
                                           indeg, rowstart);
    k_place  <<<NB, 1024, 0, stream>>>(pairbuf, rowstart, col);

    // conv1 dense projection (weight_first since 128>32)
    k_gemm1<<<N / 8, 256, 0, stream>>>(in_feat, W1, out_norm, bufA);

    // conv1 aggregate: bufA -> bufB, res = agg*in_norm + b1, pre-scaled by out_norm
    k_spmm<0, 0><<<N / 8, 256, 0, stream>>>(bufA, rowstart, indeg, col, in_norm,
                                            out_norm, W2, b1, bufB);

    // 6 middle convs: ping-pong B->A->B->...
    float* cur = bufB; float* nxt = bufA;
    for (int i = 0; i < 6; ++i) {
        k_spmm<1, 0><<<N / 8, 256, 0, stream>>>(cur, rowstart, indeg, col, in_norm,
                                                out_norm, W2, b2, nxt);
        float* tmp = cur; cur = nxt; nxt = tmp;
    }
    // final conv: cur -> out (no out_norm pre-scale, raw h)
    k_spmm<1, 1><<<N / 8, 256, 0, stream>>>(cur, rowstart, indeg, col, in_norm,
                                            out_norm, W2, b2, out);
}

// Round 8
// 655.752 us; speedup vs baseline: 2.3652x; 1.0664x over previous
//
#include <hip/hip_runtime.h>
#include <hip/hip_bf16.h>

#define NNODES 100000
#define NEDGES 3200000
#define INF 128
#define HID 32
#define NB 392                                 // buckets: node>>8, 256 nodes each
#define BSHIFT 8
#define NPB 256                                // nodes per bucket
#define CNT_BLOCKS ((NEDGES + 2047) / 2048)    // 1563

// ---- pass 1: per-block LDS bucket histograms -> global bucket counts ----
__global__ void k_cnt(const int* __restrict__ src, const int* __restrict__ dst,
                      int* __restrict__ bcnt_src, int* __restrict__ bcnt_dst) {
    __shared__ int hs[NB], hd[NB];
    int tid = threadIdx.x;
    for (int i = tid; i < NB; i += 256) { hs[i] = 0; hd[i] = 0; }
    __syncthreads();
    int start = blockIdx.x * 2048;
#pragma unroll
    for (int k = 0; k < 8; ++k) {
        int i = start + tid + k * 256;
        if (i < NEDGES) {
            atomicAdd(&hs[src[i] >> BSHIFT], 1);
            atomicAdd(&hd[dst[i] >> BSHIFT], 1);
        }
    }
    __syncthreads();
    for (int i = tid; i < NB; i += 256) {
        if (hs[i]) atomicAdd(&bcnt_src[i], hs[i]);
        if (hd[i]) atomicAdd(&bcnt_dst[i], hd[i]);
    }
}

// ---- pass 2: exclusive scan of the NB-entry bucket counts (both sides) ----
__global__ void k_bscan(const int* __restrict__ bcnt_src, const int* __restrict__ bcnt_dst,
                        int* __restrict__ bbase_src, int* __restrict__ bbase_dst,
                        int* __restrict__ gcur_src, int* __restrict__ gcur_dst) {
    __shared__ int s[512], t[512];
    int tid = threadIdx.x;
    int vs = (tid < NB) ? bcnt_src[tid] : 0;
    int vd = (tid < NB) ? bcnt_dst[tid] : 0;
    s[tid] = vs; t[tid] = vd;
    __syncthreads();
    for (int off = 1; off < 512; off <<= 1) {
        int a = (tid >= off) ? s[tid - off] : 0;
        int b = (tid >= off) ? t[tid - off] : 0;
        __syncthreads();
        s[tid] += a; t[tid] += b;
        __syncthreads();
    }
    if (tid < NB) {
        bbase_src[tid] = s[tid] - vs;  gcur_src[tid] = s[tid] - vs;
        bbase_dst[tid] = t[tid] - vd;  gcur_dst[tid] = t[tid] - vd;
    }
}

// ---- pass 3: partition edges: (dst,src) pairs by dst-bucket, src vals by src-bucket
__global__ void k_bucket2(const int* __restrict__ src, const int* __restrict__ dst,
                          int* __restrict__ gcur_src, int* __restrict__ gcur_dst,
                          int2* __restrict__ pairbuf, int* __restrict__ srctmp) {
    __shared__ int hs[NB], hd[NB], bs[NB], bd[NB];
    int tid = threadIdx.x;
    for (int i = tid; i < NB; i += 256) { hs[i] = 0; hd[i] = 0; }
    __syncthreads();
    int start = blockIdx.x * 2048;
    int d8[8], s8[8], rs8[8], rd8[8];
#pragma unroll
    for (int k = 0; k < 8; ++k) {
        int i = start + tid + k * 256;
        d8[k] = -1;
        if (i < NEDGES) {
            int d = dst[i], s = src[i];
            d8[k] = d; s8[k] = s;
            rd8[k] = atomicAdd(&hd[d >> BSHIFT], 1);
            rs8[k] = atomicAdd(&hs[s >> BSHIFT], 1);
        }
    }
    __syncthreads();
    for (int i = tid; i < NB; i += 256) {
        bs[i] = hs[i] ? atomicAdd(&gcur_src[i], hs[i]) : 0;
        bd[i] = hd[i] ? atomicAdd(&gcur_dst[i], hd[i]) : 0;
    }
    __syncthreads();
#pragma unroll
    for (int k = 0; k < 8; ++k) {
        if (d8[k] >= 0) {
            int2 e; e.x = d8[k]; e.y = s8[k];
            pairbuf[bd[d8[k] >> BSHIFT] + rd8[k]] = e;
            srctmp[bs[s8[k] >> BSHIFT] + rs8[k]] = s8[k];
        }
    }
}

// ---- pass 4: per-bucket node stats. b<NB: src-phase (out_norm); else dst-phase
//      (indeg, in_norm, rowstart via 256-wide in-block scan).
__global__ void k_nodes(const int* __restrict__ srctmp, const int2* __restrict__ pairbuf,
                        const int* __restrict__ bbase_src, const int* __restrict__ bcnt_src,
                        const int* __restrict__ bbase_dst, const int* __restrict__ bcnt_dst,
                        float* __restrict__ out_norm, float* __restrict__ in_norm,
                        int* __restrict__ indeg, int* __restrict__ rowstart) {
    __shared__ int cnt[NPB];
    __shared__ int ss[NPB];
    int tid = threadIdx.x;
    int b = blockIdx.x;
    int srcphase = (b < NB);
    int bb = srcphase ? b : b - NB;
    int node0 = bb * NPB;
    cnt[tid] = 0;
    __syncthreads();
    if (srcphase) {
        int s0 = bbase_src[bb], n = bcnt_src[bb];
        for (int i = tid; i < n; i += 256)
            atomicAdd(&cnt[srctmp[s0 + i] - node0], 1);
        __syncthreads();
        int nn = node0 + tid;
        if (nn < NNODES) {
            int c = cnt[tid];
            out_norm[nn] = rsqrtf((float)(c > 1 ? c : 1));
        }
    } else {
        int d0 = bbase_dst[bb], n = bcnt_dst[bb];
        for (int i = tid; i < n; i += 256)
            atomicAdd(&cnt[pairbuf[d0 + i].x - node0], 1);
        __syncthreads();
        int c = cnt[tid];
        ss[tid] = c;
        __syncthreads();
        for (int off = 1; off < 256; off <<= 1) {
            int t = (tid >= off) ? ss[tid - off] : 0;
            __syncthreads();
            ss[tid] += t;
            __syncthreads();
        }
        int excl = ss[tid] - c;
        int nn = node0 + tid;
        if (nn < NNODES) {
            indeg[nn] = c;
            in_norm[nn] = rsqrtf((float)(c > 1 ? c : 1));
            rowstart[nn] = d0 + excl;
        }
    }
}

// ---- pass 5: within-bucket placement; col window is one bucket (~32KB), L2-local --
__global__ void k_place(const int2* __restrict__ pairbuf, const int* __restrict__ rowstart,
                        int* __restrict__ col) {
    __shared__ int cur[NPB];
    int tid = threadIdx.x;
    int bucket = blockIdx.x;
    int node0 = bucket * NPB;
    if (node0 >= NNODES) return;               // empty trailing bucket
    int n = node0 + tid;
    cur[tid] = (n < NNODES) ? rowstart[n] : 0;
    __syncthreads();
    int pstart = rowstart[node0];
    int pend   = (node0 + NPB >= NNODES) ? NEDGES : rowstart[node0 + NPB];
    for (int i = pstart + tid; i < pend; i += 256) {
        int2 e = pairbuf[i];
        int pos = atomicAdd(&cur[e.x - node0], 1);
        col[pos] = e.y;
    }
}

// ---------------- conv1 dense part: t[n] = out_norm[n] * (x[n] @ W1) ----------------
__global__ void k_gemm1(const float* __restrict__ x, const float* __restrict__ W1,
                        const float* __restrict__ out_norm, float* __restrict__ t) {
    __shared__ float wlds[INF * HID];          // 16 KB
    __shared__ float xlds[8][INF];             // 4 KB
    int tid = threadIdx.x;
    for (int i = tid; i < INF * HID; i += 256) wlds[i] = W1[i];
    int group = tid >> 5, lane = tid & 31;
    int row = blockIdx.x * 8 + group;          // grid = N/8 exact (12500)
    float4 xv = ((const float4*)(x + (size_t)row * INF))[lane];
    ((float4*)xlds[group])[lane] = xv;
    __syncthreads();
    float acc = 0.f;
#pragma unroll
    for (int k = 0; k < INF; ++k)
        acc += xlds[group][k] * wlds[k * HID + lane];
    t[(size_t)row * HID + lane] = acc * out_norm[row];
}

// ---------------- fused SpMM step — float4 gather (round-7 form, untouched) --------
template<int APPLY_W, int FINAL>
__global__ void k_spmm(const float* __restrict__ gin, const int* __restrict__ rowstart,
                       const int* __restrict__ indeg, const int* __restrict__ col,
                       const float* __restrict__ in_norm, const float* __restrict__ out_norm,
                       const float* __restrict__ W, const float* __restrict__ bias,
                       float* __restrict__ gout) {
    __shared__ float wlds[HID * HID];          // 4 KB
    __shared__ float sh[8][HID];
    int tid = threadIdx.x, lane = tid & 31, group = tid >> 5;
    int g = lane >> 3, f = lane & 7;
    if (APPLY_W) {
        for (int i = tid; i < HID * HID; i += 256) wlds[i] = W[i];
        __syncthreads();
    }
    int n = blockIdx.x * 8 + group;            // grid = N/8 exact
    int start = rowstart[n];
    int deg   = indeg[n];
    const float4* gin4 = (const float4*)gin;

    float4 acc = make_float4(0.f, 0.f, 0.f, 0.f);
    int base = 0;
    for (; base + 32 <= deg; base += 32) {     // full chunks: no predication
        int c = col[start + base + lane];
#pragma unroll
        for (int t = 0; t < 8; ++t) {
            int s = __shfl(c, t * 4 + g, 32);
            float4 v = gin4[(size_t)s * 8 + f];
            acc.x += v.x; acc.y += v.y; acc.z += v.z; acc.w += v.w;
        }
    }
    if (base < deg) {                          // tail chunk (rem in 1..31)
        int rem = deg - base;
        int c = (base + lane < deg) ? col[start + base + lane] : 0;
#pragma unroll
        for (int t = 0; t < 8; ++t) {
            if (t * 4 < rem) {
                int e = t * 4 + g;
                int s = __shfl(c, e, 32);
                float4 v = gin4[(size_t)s * 8 + f];
                float m = (e < rem) ? 1.f : 0.f;
                acc.x = fmaf(m, v.x, acc.x);
                acc.y = fmaf(m, v.y, acc.y);
                acc.z = fmaf(m, v.z, acc.z);
                acc.w = fmaf(m, v.w, acc.w);
            }
        }
    }
    // reduce the 4 edge-subgroups (lane bits 3,4)
    acc.x += __shfl_xor(acc.x, 8, 32);  acc.y += __shfl_xor(acc.y, 8, 32);
    acc.z += __shfl_xor(acc.z, 8, 32);  acc.w += __shfl_xor(acc.w, 8, 32);
    acc.x += __shfl_xor(acc.x, 16, 32); acc.y += __shfl_xor(acc.y, 16, 32);
    acc.z += __shfl_xor(acc.z, 16, 32); acc.w += __shfl_xor(acc.w, 16, 32);

    float inm = in_norm[n];
    acc.x *= inm; acc.y *= inm; acc.z *= inm; acc.w *= inm;
    if (g == 0) *(float4*)&sh[group][4 * f] = acc;   // same-wave LDS fill

    float res;
    if (APPLY_W) {
        float o = bias[lane];
#pragma unroll
        for (int k = 0; k < HID; ++k)
            o += sh[group][k] * wlds[k * HID + lane];
        res = o;
    } else {
        res = sh[group][lane] + bias[lane];
    }
    if (FINAL) gout[(size_t)n * HID + lane] = res;
    else       gout[(size_t)n * HID + lane] = res * out_norm[n];
}

extern "C" void kernel_launch(void* const* d_in, const int* in_sizes, int n_in,
                              void* d_out, int out_size, void* d_ws, size_t ws_size,
                              hipStream_t stream) {
    const float* in_feat = (const float*)d_in[0];
    const float* W1      = (const float*)d_in[1];
    const float* b1      = (const float*)d_in[2];
    const float* W2      = (const float*)d_in[3];
    const float* b2      = (const float*)d_in[4];
    const int*   src     = (const int*)d_in[5];
    const int*   dst     = (const int*)d_in[6];
    float*       out     = (float*)d_out;

    const int N = NNODES, E = NEDGES;
    // workspace layout (4-byte units)
    int* bcnt_src  = (int*)d_ws;                // 512
    int* bcnt_dst  = bcnt_src + 512;            // 512
    int* bbase_src = bcnt_dst + 512;            // 512
    int* bbase_dst = bbase_src + 512;           // 512
    int* gcur_src  = bbase_dst + 512;           // 512
    int* gcur_dst  = gcur_src + 512;            // 512
    int* indeg     = gcur_dst + 512;            // N
    int* rowstart  = indeg + N;                 // N
    float* out_norm = (float*)(rowstart + N);   // N
    float* in_norm  = out_norm + N;             // N
    int*   col      = (int*)(in_norm + N);      // E   (aliased as srctmp pre-place)
    float* bufA     = (float*)(col + E);        // N*HID (aliased by pairbuf pre-gemm)
    float* bufB     = bufA + (size_t)N * HID;   // N*HID
    int2*  pairbuf  = (int2*)bufA;              // E pairs = exactly bufA+bufB
    int*   srctmp   = col;                      // E ints, consumed before col written
    size_t need = ((size_t)3072 + 4 * N + E + (size_t)2 * N * HID) * 4;
    if (ws_size < need) return;                 // fail visibly rather than corrupt

    hipMemsetAsync(bcnt_src, 0, 1024 * sizeof(int), stream);  // bcnt_src + bcnt_dst

    k_cnt    <<<CNT_BLOCKS, 256, 0, stream>>>(src, dst, bcnt_src, bcnt_dst);
    k_bscan  <<<1, 512, 0, stream>>>(bcnt_src, bcnt_dst, bbase_src, bbase_dst,
                                     gcur_src, gcur_dst);
    k_bucket2<<<CNT_BLOCKS, 256, 0, stream>>>(src, dst, gcur_src, gcur_dst,
                                              pairbuf, srctmp);
    k_nodes  <<<2 * NB, 256, 0, stream>>>(srctmp, pairbuf, bbase_src, bcnt_src,
                                          bbase_dst, bcnt_dst, out_norm, in_norm,
                                          indeg, rowstart);
    k_place  <<<NB, 256, 0, stream>>>(pairbuf, rowstart, col);

    // conv1 dense projection (weight_first since 128>32)
    k_gemm1<<<N / 8, 256, 0, stream>>>(in_feat, W1, out_norm, bufA);

    // conv1 aggregate: bufA -> bufB, res = agg*in_norm + b1, pre-scaled by out_norm
    k_spmm<0, 0><<<N / 8, 256, 0, stream>>>(bufA, rowstart, indeg, col, in_norm,
                                            out_norm, W2, b1, bufB);

    // 6 middle convs: ping-pong B->A->B->...
    float* cur = bufB; float* nxt = bufA;
    for (int i = 0; i < 6; ++i) {
        k_spmm<1, 0><<<N / 8, 256, 0, stream>>>(cur, rowstart, indeg, col, in_norm,
                                                out_norm, W2, b2, nxt);
        float* tmp = cur; cur = nxt; nxt = tmp;
    }
    // final conv: cur -> out (no out_norm pre-scale, raw h)
    k_spmm<1, 1><<<N / 8, 256, 0, stream>>>(cur, rowstart, indeg, col, in_norm,
                                            out_norm, W2, b2, out);
}

// Round 9
// 653.185 us; speedup vs baseline: 2.3745x; 1.0039x over previous
//
#include <hip/hip_runtime.h>
#include <hip/hip_bf16.h>

#define NNODES 100000
#define NEDGES 3200000
#define INF 128
#define HID 32
#define NB 392                                 // buckets: node>>8, 256 nodes each
#define BSHIFT 8
#define NPB 256                                // nodes per bucket
#define BATCH 16384                            // edges per partition block
#define PART_BLOCKS ((NEDGES + BATCH - 1) / BATCH)  // 196

// ---- pass 1: per-block LDS bucket histograms -> global bucket counts ----
__global__ void k_cnt(const int* __restrict__ src, const int* __restrict__ dst,
                      int* __restrict__ bcnt_src, int* __restrict__ bcnt_dst) {
    __shared__ int hs[NB], hd[NB];
    int tid = threadIdx.x;
    for (int i = tid; i < NB; i += 256) { hs[i] = 0; hd[i] = 0; }
    __syncthreads();
    int start = blockIdx.x * BATCH;
    int end = start + BATCH; if (end > NEDGES) end = NEDGES;
    for (int i = start + tid; i < end; i += 256) {
        atomicAdd(&hs[src[i] >> BSHIFT], 1);
        atomicAdd(&hd[dst[i] >> BSHIFT], 1);
    }
    __syncthreads();
    for (int i = tid; i < NB; i += 256) {
        if (hs[i]) atomicAdd(&bcnt_src[i], hs[i]);
        if (hd[i]) atomicAdd(&bcnt_dst[i], hd[i]);
    }
}

// ---- pass 2: exclusive scan of the NB-entry bucket counts (both sides) ----
__global__ void k_bscan(const int* __restrict__ bcnt_src, const int* __restrict__ bcnt_dst,
                        int* __restrict__ bbase_src, int* __restrict__ bbase_dst,
                        int* __restrict__ gcur_src, int* __restrict__ gcur_dst) {
    __shared__ int s[512], t[512];
    int tid = threadIdx.x;
    int vs = (tid < NB) ? bcnt_src[tid] : 0;
    int vd = (tid < NB) ? bcnt_dst[tid] : 0;
    s[tid] = vs; t[tid] = vd;
    __syncthreads();
    for (int off = 1; off < 512; off <<= 1) {
        int a = (tid >= off) ? s[tid - off] : 0;
        int b = (tid >= off) ? t[tid - off] : 0;
        __syncthreads();
        s[tid] += a; t[tid] += b;
        __syncthreads();
    }
    if (tid < NB) {
        bbase_src[tid] = s[tid] - vs;  gcur_src[tid] = s[tid] - vs;
        bbase_dst[tid] = t[tid] - vd;  gcur_dst[tid] = t[tid] - vd;
    }
}

// ---- pass 3: partition edges. Two passes over a 16K-edge batch: LDS histogram,
//      reserve contiguous global chunk per bucket (~42 pairs = 334B -> ~1.2x write
//      amp vs the 5-pair/42B chunks that caused 3.5x), then re-read (L2-hot) and
//      place via LDS cursors. No per-edge register state.
__global__ void k_bucket2(const int* __restrict__ src, const int* __restrict__ dst,
                          int* __restrict__ gcur_src, int* __restrict__ gcur_dst,
                          int2* __restrict__ pairbuf, int* __restrict__ srctmp) {
    __shared__ int cs[NB], cd[NB];             // histogram, then global cursor
    int tid = threadIdx.x;
    for (int i = tid; i < NB; i += 256) { cs[i] = 0; cd[i] = 0; }
    __syncthreads();
    int start = blockIdx.x * BATCH;
    int end = start + BATCH; if (end > NEDGES) end = NEDGES;
    for (int i = start + tid; i < end; i += 256) {
        atomicAdd(&cs[src[i] >> BSHIFT], 1);
        atomicAdd(&cd[dst[i] >> BSHIFT], 1);
    }
    __syncthreads();
    for (int i = tid; i < NB; i += 256) {
        int c = cs[i];
        cs[i] = c ? atomicAdd(&gcur_src[i], c) : 0;
        c = cd[i];
        cd[i] = c ? atomicAdd(&gcur_dst[i], c) : 0;
    }
    __syncthreads();
    for (int i = start + tid; i < end; i += 256) {
        int d = dst[i], s = src[i];
        int pd = atomicAdd(&cd[d >> BSHIFT], 1);
        int2 e; e.x = d; e.y = s;
        pairbuf[pd] = e;
        int ps = atomicAdd(&cs[s >> BSHIFT], 1);
        srctmp[ps] = s;
    }
}

// ---- pass 4: per-bucket node stats. b<NB: src-phase (out_norm); else dst-phase
__global__ void k_nodes(const int* __restrict__ srctmp, const int2* __restrict__ pairbuf,
                        const int* __restrict__ bbase_src, const int* __restrict__ bcnt_src,
                        const int* __restrict__ bbase_dst, const int* __restrict__ bcnt_dst,
                        float* __restrict__ out_norm, float* __restrict__ in_norm,
                        int* __restrict__ indeg, int* __restrict__ rowstart) {
    __shared__ int cnt[NPB];
    __shared__ int ss[NPB];
    int tid = threadIdx.x;
    int b = blockIdx.x;
    int srcphase = (b < NB);
    int bb = srcphase ? b : b - NB;
    int node0 = bb * NPB;
    cnt[tid] = 0;
    __syncthreads();
    if (srcphase) {
        int s0 = bbase_src[bb], n = bcnt_src[bb];
        for (int i = tid; i < n; i += 256)
            atomicAdd(&cnt[srctmp[s0 + i] - node0], 1);
        __syncthreads();
        int nn = node0 + tid;
        if (nn < NNODES) {
            int c = cnt[tid];
            out_norm[nn] = rsqrtf((float)(c > 1 ? c : 1));
        }
    } else {
        int d0 = bbase_dst[bb], n = bcnt_dst[bb];
        for (int i = tid; i < n; i += 256)
            atomicAdd(&cnt[pairbuf[d0 + i].x - node0], 1);
        __syncthreads();
        int c = cnt[tid];
        ss[tid] = c;
        __syncthreads();
        for (int off = 1; off < 256; off <<= 1) {
            int t = (tid >= off) ? ss[tid - off] : 0;
            __syncthreads();
            ss[tid] += t;
            __syncthreads();
        }
        int excl = ss[tid] - c;
        int nn = node0 + tid;
        if (nn < NNODES) {
            indeg[nn] = c;
            in_norm[nn] = rsqrtf((float)(c > 1 ? c : 1));
            rowstart[nn] = d0 + excl;
        }
    }
}

// ---- pass 5: within-bucket placement; col window is one bucket (~32KB), L2-local --
__global__ void k_place(const int2* __restrict__ pairbuf, const int* __restrict__ rowstart,
                        int* __restrict__ col) {
    __shared__ int cur[NPB];
    int tid = threadIdx.x;
    int bucket = blockIdx.x;
    int node0 = bucket * NPB;
    if (node0 >= NNODES) return;               // empty trailing bucket
    int n = node0 + tid;
    cur[tid] = (n < NNODES) ? rowstart[n] : 0;
    __syncthreads();
    int pstart = rowstart[node0];
    int pend   = (node0 + NPB >= NNODES) ? NEDGES : rowstart[node0 + NPB];
    for (int i = pstart + tid; i < pend; i += 256) {
        int2 e = pairbuf[i];
        int pos = atomicAdd(&cur[e.x - node0], 1);
        col[pos] = e.y;
    }
}

// ---------------- conv1 dense part: t[n] = out_norm[n] * (x[n] @ W1) ----------------
__global__ void k_gemm1(const float* __restrict__ x, const float* __restrict__ W1,
                        const float* __restrict__ out_norm, float* __restrict__ t) {
    __shared__ float wlds[INF * HID];          // 16 KB
    __shared__ float xlds[8][INF];             // 4 KB
    int tid = threadIdx.x;
    for (int i = tid; i < INF * HID; i += 256) wlds[i] = W1[i];
    int group = tid >> 5, lane = tid & 31;
    int row = blockIdx.x * 8 + group;          // grid = N/8 exact (12500)
    float4 xv = ((const float4*)(x + (size_t)row * INF))[lane];
    ((float4*)xlds[group])[lane] = xv;
    __syncthreads();
    float acc = 0.f;
#pragma unroll
    for (int k = 0; k < INF; ++k)
        acc += xlds[group][k] * wlds[k * HID + lane];
    t[(size_t)row * HID + lane] = acc * out_norm[row];
}

// ---------------- fused SpMM step — float4 gather (round-7 form, untouched) --------
template<int APPLY_W, int FINAL>
__global__ void k_spmm(const float* __restrict__ gin, const int* __restrict__ rowstart,
                       const int* __restrict__ indeg, const int* __restrict__ col,
                       const float* __restrict__ in_norm, const float* __restrict__ out_norm,
                       const float* __restrict__ W, const float* __restrict__ bias,
                       float* __restrict__ gout) {
    __shared__ float wlds[HID * HID];          // 4 KB
    __shared__ float sh[8][HID];
    int tid = threadIdx.x, lane = tid & 31, group = tid >> 5;
    int g = lane >> 3, f = lane & 7;
    if (APPLY_W) {
        for (int i = tid; i < HID * HID; i += 256) wlds[i] = W[i];
        __syncthreads();
    }
    int n = blockIdx.x * 8 + group;            // grid = N/8 exact
    int start = rowstart[n];
    int deg   = indeg[n];
    const float4* gin4 = (const float4*)gin;

    float4 acc = make_float4(0.f, 0.f, 0.f, 0.f);
    int base = 0;
    for (; base + 32 <= deg; base += 32) {     // full chunks: no predication
        int c = col[start + base + lane];
#pragma unroll
        for (int t = 0; t < 8; ++t) {
            int s = __shfl(c, t * 4 + g, 32);
            float4 v = gin4[(size_t)s * 8 + f];
            acc.x += v.x; acc.y += v.y; acc.z += v.z; acc.w += v.w;
        }
    }
    if (base < deg) {                          // tail chunk (rem in 1..31)
        int rem = deg - base;
        int c = (base + lane < deg) ? col[start + base + lane] : 0;
#pragma unroll
        for (int t = 0; t < 8; ++t) {
            if (t * 4 < rem) {
                int e = t * 4 + g;
                int s = __shfl(c, e, 32);
                float4 v = gin4[(size_t)s * 8 + f];
                float m = (e < rem) ? 1.f : 0.f;
                acc.x = fmaf(m, v.x, acc.x);
                acc.y = fmaf(m, v.y, acc.y);
                acc.z = fmaf(m, v.z, acc.z);
                acc.w = fmaf(m, v.w, acc.w);
            }
        }
    }
    // reduce the 4 edge-subgroups (lane bits 3,4)
    acc.x += __shfl_xor(acc.x, 8, 32);  acc.y += __shfl_xor(acc.y, 8, 32);
    acc.z += __shfl_xor(acc.z, 8, 32);  acc.w += __shfl_xor(acc.w, 8, 32);
    acc.x += __shfl_xor(acc.x, 16, 32); acc.y += __shfl_xor(acc.y, 16, 32);
    acc.z += __shfl_xor(acc.z, 16, 32); acc.w += __shfl_xor(acc.w, 16, 32);

    float inm = in_norm[n];
    acc.x *= inm; acc.y *= inm; acc.z *= inm; acc.w *= inm;
    if (g == 0) *(float4*)&sh[group][4 * f] = acc;   // same-wave LDS fill

    float res;
    if (APPLY_W) {
        float o = bias[lane];
#pragma unroll
        for (int k = 0; k < HID; ++k)
            o += sh[group][k] * wlds[k * HID + lane];
        res = o;
    } else {
        res = sh[group][lane] + bias[lane];
    }
    if (FINAL) gout[(size_t)n * HID + lane] = res;
    else       gout[(size_t)n * HID + lane] = res * out_norm[n];
}

extern "C" void kernel_launch(void* const* d_in, const int* in_sizes, int n_in,
                              void* d_out, int out_size, void* d_ws, size_t ws_size,
                              hipStream_t stream) {
    const float* in_feat = (const float*)d_in[0];
    const float* W1      = (const float*)d_in[1];
    const float* b1      = (const float*)d_in[2];
    const float* W2      = (const float*)d_in[3];
    const float* b2      = (const float*)d_in[4];
    const int*   src     = (const int*)d_in[5];
    const int*   dst     = (const int*)d_in[6];
    float*       out     = (float*)d_out;

    const int N = NNODES, E = NEDGES;
    // workspace layout (4-byte units)
    int* bcnt_src  = (int*)d_ws;                // 512
    int* bcnt_dst  = bcnt_src + 512;            // 512
    int* bbase_src = bcnt_dst + 512;            // 512
    int* bbase_dst = bbase_src + 512;           // 512
    int* gcur_src  = bbase_dst + 512;           // 512
    int* gcur_dst  = gcur_src + 512;            // 512
    int* indeg     = gcur_dst + 512;            // N
    int* rowstart  = indeg + N;                 // N
    float* out_norm = (float*)(rowstart + N);   // N
    float* in_norm  = out_norm + N;             // N
    int*   col      = (int*)(in_norm + N);      // E   (aliased as srctmp pre-place)
    float* bufA     = (float*)(col + E);        // N*HID (aliased by pairbuf pre-gemm)
    float* bufB     = bufA + (size_t)N * HID;   // N*HID
    int2*  pairbuf  = (int2*)bufA;              // E pairs = exactly bufA+bufB
    int*   srctmp   = col;                      // E ints, consumed before col written
    size_t need = ((size_t)3072 + 4 * N + E + (size_t)2 * N * HID) * 4;
    if (ws_size < need) return;                 // fail visibly rather than corrupt

    hipMemsetAsync(bcnt_src, 0, 1024 * sizeof(int), stream);  // bcnt_src + bcnt_dst

    k_cnt    <<<PART_BLOCKS, 256, 0, stream>>>(src, dst, bcnt_src, bcnt_dst);
    k_bscan  <<<1, 512, 0, stream>>>(bcnt_src, bcnt_dst, bbase_src, bbase_dst,
                                     gcur_src, gcur_dst);
    k_bucket2<<<PART_BLOCKS, 256, 0, stream>>>(src, dst, gcur_src, gcur_dst,
                                               pairbuf, srctmp);
    k_nodes  <<<2 * NB, 256, 0, stream>>>(srctmp, pairbuf, bbase_src, bcnt_src,
                                          bbase_dst, bcnt_dst, out_norm, in_norm,
                                          indeg, rowstart);
    k_place  <<<NB, 256, 0, stream>>>(pairbuf, rowstart, col);

    // conv1 dense projection (weight_first since 128>32)
    k_gemm1<<<N / 8, 256, 0, stream>>>(in_feat, W1, out_norm, bufA);

    // conv1 aggregate: bufA -> bufB, res = agg*in_norm + b1, pre-scaled by out_norm
    k_spmm<0, 0><<<N / 8, 256, 0, stream>>>(bufA, rowstart, indeg, col, in_norm,
                                            out_norm, W2, b1, bufB);

    // 6 middle convs: ping-pong B->A->B->...
    float* cur = bufB; float* nxt = bufA;
    for (int i = 0; i < 6; ++i) {
        k_spmm<1, 0><<<N / 8, 256, 0, stream>>>(cur, rowstart, indeg, col, in_norm,
                                                out_norm, W2, b2, nxt);
        float* tmp = cur; cur = nxt; nxt = tmp;
    }
    // final conv: cur -> out (no out_norm pre-scale, raw h)
    k_spmm<1, 1><<<N / 8, 256, 0, stream>>>(cur, rowstart, indeg, col, in_norm,
                                            out_norm, W2, b2, out);
}

// Round 10
// 613.712 us; speedup vs baseline: 2.5272x; 1.0643x over previous
//
#include <hip/hip_runtime.h>
#include <hip/hip_bf16.h>

#define NNODES 100000
#define NEDGES 3200000
#define INF 128
#define HID 32
#define NB 392                                 // buckets: node>>8, 256 nodes each
#define BSHIFT 8
#define NPB 256                                // nodes per bucket
#define BATCH 16384                            // edges per partition block
#define PART_BLOCKS ((NEDGES + BATCH - 1) / BATCH)  // 196

// ---- pass 1: per-block LDS bucket histograms -> global bucket counts ----
// 1024 threads: round-9 showed 256-thread version at 7% occupancy, latency-bound.
__global__ void k_cnt(const int* __restrict__ src, const int* __restrict__ dst,
                      int* __restrict__ bcnt_src, int* __restrict__ bcnt_dst) {
    __shared__ int hs[NB], hd[NB];
    int tid = threadIdx.x;
    for (int i = tid; i < NB; i += 1024) { hs[i] = 0; hd[i] = 0; }
    __syncthreads();
    int start = blockIdx.x * BATCH;
    int end = start + BATCH; if (end > NEDGES) end = NEDGES;
    for (int i = start + tid; i < end; i += 1024) {
        atomicAdd(&hs[src[i] >> BSHIFT], 1);
        atomicAdd(&hd[dst[i] >> BSHIFT], 1);
    }
    __syncthreads();
    for (int i = tid; i < NB; i += 1024) {
        if (hs[i]) atomicAdd(&bcnt_src[i], hs[i]);
        if (hd[i]) atomicAdd(&bcnt_dst[i], hd[i]);
    }
}

// ---- pass 2: exclusive scan of the NB-entry bucket counts (both sides) ----
__global__ void k_bscan(const int* __restrict__ bcnt_src, const int* __restrict__ bcnt_dst,
                        int* __restrict__ bbase_src, int* __restrict__ bbase_dst,
                        int* __restrict__ gcur_src, int* __restrict__ gcur_dst) {
    __shared__ int s[512], t[512];
    int tid = threadIdx.x;
    int vs = (tid < NB) ? bcnt_src[tid] : 0;
    int vd = (tid < NB) ? bcnt_dst[tid] : 0;
    s[tid] = vs; t[tid] = vd;
    __syncthreads();
    for (int off = 1; off < 512; off <<= 1) {
        int a = (tid >= off) ? s[tid - off] : 0;
        int b = (tid >= off) ? t[tid - off] : 0;
        __syncthreads();
        s[tid] += a; t[tid] += b;
        __syncthreads();
    }
    if (tid < NB) {
        bbase_src[tid] = s[tid] - vs;  gcur_src[tid] = s[tid] - vs;
        bbase_dst[tid] = t[tid] - vd;  gcur_dst[tid] = t[tid] - vd;
    }
}

// ---- pass 3: partition edges. Two passes over a 16K-edge batch: LDS histogram,
//      reserve contiguous global chunk per bucket, re-read (L2-hot) and place via
//      LDS cursors. 1024 threads for latency hiding (was 7% occupancy at 256).
__global__ void k_bucket2(const int* __restrict__ src, const int* __restrict__ dst,
                          int* __restrict__ gcur_src, int* __restrict__ gcur_dst,
                          int2* __restrict__ pairbuf, int* __restrict__ srctmp) {
    __shared__ int cs[NB], cd[NB];             // histogram, then global cursor
    int tid = threadIdx.x;
    for (int i = tid; i < NB; i += 1024) { cs[i] = 0; cd[i] = 0; }
    __syncthreads();
    int start = blockIdx.x * BATCH;
    int end = start + BATCH; if (end > NEDGES) end = NEDGES;
    for (int i = start + tid; i < end; i += 1024) {
        atomicAdd(&cs[src[i] >> BSHIFT], 1);
        atomicAdd(&cd[dst[i] >> BSHIFT], 1);
    }
    __syncthreads();
    for (int i = tid; i < NB; i += 1024) {
        int c = cs[i];
        cs[i] = c ? atomicAdd(&gcur_src[i], c) : 0;
        c = cd[i];
        cd[i] = c ? atomicAdd(&gcur_dst[i], c) : 0;
    }
    __syncthreads();
    for (int i = start + tid; i < end; i += 1024) {
        int d = dst[i], s = src[i];
        int pd = atomicAdd(&cd[d >> BSHIFT], 1);
        int2 e; e.x = d; e.y = s;
        pairbuf[pd] = e;
        int ps = atomicAdd(&cs[s >> BSHIFT], 1);
        srctmp[ps] = s;
    }
}

// ---- pass 4: per-bucket node stats. b<NB: src-phase (out_norm); else dst-phase
__global__ void k_nodes(const int* __restrict__ srctmp, const int2* __restrict__ pairbuf,
                        const int* __restrict__ bbase_src, const int* __restrict__ bcnt_src,
                        const int* __restrict__ bbase_dst, const int* __restrict__ bcnt_dst,
                        float* __restrict__ out_norm, float* __restrict__ in_norm,
                        int* __restrict__ indeg, int* __restrict__ rowstart) {
    __shared__ int cnt[NPB];
    __shared__ int ss[NPB];
    int tid = threadIdx.x;
    int b = blockIdx.x;
    int srcphase = (b < NB);
    int bb = srcphase ? b : b - NB;
    int node0 = bb * NPB;
    cnt[tid] = 0;
    __syncthreads();
    if (srcphase) {
        int s0 = bbase_src[bb], n = bcnt_src[bb];
        for (int i = tid; i < n; i += 256)
            atomicAdd(&cnt[srctmp[s0 + i] - node0], 1);
        __syncthreads();
        int nn = node0 + tid;
        if (nn < NNODES) {
            int c = cnt[tid];
            out_norm[nn] = rsqrtf((float)(c > 1 ? c : 1));
        }
    } else {
        int d0 = bbase_dst[bb], n = bcnt_dst[bb];
        for (int i = tid; i < n; i += 256)
            atomicAdd(&cnt[pairbuf[d0 + i].x - node0], 1);
        __syncthreads();
        int c = cnt[tid];
        ss[tid] = c;
        __syncthreads();
        for (int off = 1; off < 256; off <<= 1) {
            int t = (tid >= off) ? ss[tid - off] : 0;
            __syncthreads();
            ss[tid] += t;
            __syncthreads();
        }
        int excl = ss[tid] - c;
        int nn = node0 + tid;
        if (nn < NNODES) {
            indeg[nn] = c;
            in_norm[nn] = rsqrtf((float)(c > 1 ? c : 1));
            rowstart[nn] = d0 + excl;
        }
    }
}

// ---- pass 5: within-bucket placement; col window is one bucket (~32KB), L2-local --
__global__ void k_place(const int2* __restrict__ pairbuf, const int* __restrict__ rowstart,
                        int* __restrict__ col) {
    __shared__ int cur[NPB];
    int tid = threadIdx.x;
    int bucket = blockIdx.x;
    int node0 = bucket * NPB;
    if (node0 >= NNODES) return;               // empty trailing bucket
    int n = node0 + tid;
    cur[tid] = (n < NNODES) ? rowstart[n] : 0;
    __syncthreads();
    int pstart = rowstart[node0];
    int pend   = (node0 + NPB >= NNODES) ? NEDGES : rowstart[node0 + NPB];
    for (int i = pstart + tid; i < pend; i += 256) {
        int2 e = pairbuf[i];
        int pos = atomicAdd(&cur[e.x - node0], 1);
        col[pos] = e.y;
    }
}

// ---------------- conv1 dense part: t[n] = out_norm[n] * (x[n] @ W1) ----------------
__global__ void k_gemm1(const float* __restrict__ x, const float* __restrict__ W1,
                        const float* __restrict__ out_norm, float* __restrict__ t) {
    __shared__ float wlds[INF * HID];          // 16 KB
    __shared__ float xlds[8][INF];             // 4 KB
    int tid = threadIdx.x;
    for (int i = tid; i < INF * HID; i += 256) wlds[i] = W1[i];
    int group = tid >> 5, lane = tid & 31;
    int row = blockIdx.x * 8 + group;          // grid = N/8 exact (12500)
    float4 xv = ((const float4*)(x + (size_t)row * INF))[lane];
    ((float4*)xlds[group])[lane] = xv;
    __syncthreads();
    float acc = 0.f;
#pragma unroll
    for (int k = 0; k < INF; ++k)
        acc += xlds[group][k] * wlds[k * HID + lane];
    t[(size_t)row * HID + lane] = acc * out_norm[row];
}

// ---------------- fused SpMM step — float4 gather (round-7 form, untouched) --------
template<int APPLY_W, int FINAL>
__global__ void k_spmm(const float* __restrict__ gin, const int* __restrict__ rowstart,
                       const int* __restrict__ indeg, const int* __restrict__ col,
                       const float* __restrict__ in_norm, const float* __restrict__ out_norm,
                       const float* __restrict__ W, const float* __restrict__ bias,
                       float* __restrict__ gout) {
    __shared__ float wlds[HID * HID];          // 4 KB
    __shared__ float sh[8][HID];
    int tid = threadIdx.x, lane = tid & 31, group = tid >> 5;
    int g = lane >> 3, f = lane & 7;
    if (APPLY_W) {
        for (int i = tid; i < HID * HID; i += 256) wlds[i] = W[i];
        __syncthreads();
    }
    int n = blockIdx.x * 8 + group;            // grid = N/8 exact
    int start = rowstart[n];
    int deg   = indeg[n];
    const float4* gin4 = (const float4*)gin;

    float4 acc = make_float4(0.f, 0.f, 0.f, 0.f);
    int base = 0;
    for (; base + 32 <= deg; base += 32) {     // full chunks: no predication
        int c = col[start + base + lane];
#pragma unroll
        for (int t = 0; t < 8; ++t) {
            int s = __shfl(c, t * 4 + g, 32);
            float4 v = gin4[(size_t)s * 8 + f];
            acc.x += v.x; acc.y += v.y; acc.z += v.z; acc.w += v.w;
        }
    }
    if (base < deg) {                          // tail chunk (rem in 1..31)
        int rem = deg - base;
        int c = (base + lane < deg) ? col[start + base + lane] : 0;
#pragma unroll
        for (int t = 0; t < 8; ++t) {
            if (t * 4 < rem) {
                int e = t * 4 + g;
                int s = __shfl(c, e, 32);
                float4 v = gin4[(size_t)s * 8 + f];
                float m = (e < rem) ? 1.f : 0.f;
                acc.x = fmaf(m, v.x, acc.x);
                acc.y = fmaf(m, v.y, acc.y);
                acc.z = fmaf(m, v.z, acc.z);
                acc.w = fmaf(m, v.w, acc.w);
            }
        }
    }
    // reduce the 4 edge-subgroups (lane bits 3,4)
    acc.x += __shfl_xor(acc.x, 8, 32);  acc.y += __shfl_xor(acc.y, 8, 32);
    acc.z += __shfl_xor(acc.z, 8, 32);  acc.w += __shfl_xor(acc.w, 8, 32);
    acc.x += __shfl_xor(acc.x, 16, 32); acc.y += __shfl_xor(acc.y, 16, 32);
    acc.z += __shfl_xor(acc.z, 16, 32); acc.w += __shfl_xor(acc.w, 16, 32);

    float inm = in_norm[n];
    acc.x *= inm; acc.y *= inm; acc.z *= inm; acc.w *= inm;
    if (g == 0) *(float4*)&sh[group][4 * f] = acc;   // same-wave LDS fill

    float res;
    if (APPLY_W) {
        float o = bias[lane];
#pragma unroll
        for (int k = 0; k < HID; ++k)
            o += sh[group][k] * wlds[k * HID + lane];
        res = o;
    } else {
        res = sh[group][lane] + bias[lane];
    }
    if (FINAL) gout[(size_t)n * HID + lane] = res;
    else       gout[(size_t)n * HID + lane] = res * out_norm[n];
}

extern "C" void kernel_launch(void* const* d_in, const int* in_sizes, int n_in,
                              void* d_out, int out_size, void* d_ws, size_t ws_size,
                              hipStream_t stream) {
    const float* in_feat = (const float*)d_in[0];
    const float* W1      = (const float*)d_in[1];
    const float* b1      = (const float*)d_in[2];
    const float* W2      = (const float*)d_in[3];
    const float* b2      = (const float*)d_in[4];
    const int*   src     = (const int*)d_in[5];
    const int*   dst     = (const int*)d_in[6];
    float*       out     = (float*)d_out;

    const int N = NNODES, E = NEDGES;
    // workspace layout (4-byte units)
    int* bcnt_src  = (int*)d_ws;                // 512
    int* bcnt_dst  = bcnt_src + 512;            // 512
    int* bbase_src = bcnt_dst + 512;            // 512
    int* bbase_dst = bbase_src + 512;           // 512
    int* gcur_src  = bbase_dst + 512;           // 512
    int* gcur_dst  = gcur_src + 512;            // 512
    int* indeg     = gcur_dst + 512;            // N
    int* rowstart  = indeg + N;                 // N
    float* out_norm = (float*)(rowstart + N);   // N
    float* in_norm  = out_norm + N;             // N
    int*   col      = (int*)(in_norm + N);      // E   (aliased as srctmp pre-place)
    float* bufA     = (float*)(col + E);        // N*HID (aliased by pairbuf pre-gemm)
    float* bufB     = bufA + (size_t)N * HID;   // N*HID
    int2*  pairbuf  = (int2*)bufA;              // E pairs = exactly bufA+bufB
    int*   srctmp   = col;                      // E ints, consumed before col written
    size_t need = ((size_t)3072 + 4 * N + E + (size_t)2 * N * HID) * 4;
    if (ws_size < need) return;                 // fail visibly rather than corrupt

    hipMemsetAsync(bcnt_src, 0, 1024 * sizeof(int), stream);  // bcnt_src + bcnt_dst

    k_cnt    <<<PART_BLOCKS, 1024, 0, stream>>>(src, dst, bcnt_src, bcnt_dst);
    k_bscan  <<<1, 512, 0, stream>>>(bcnt_src, bcnt_dst, bbase_src, bbase_dst,
                                     gcur_src, gcur_dst);
    k_bucket2<<<PART_BLOCKS, 1024, 0, stream>>>(src, dst, gcur_src, gcur_dst,
                                                pairbuf, srctmp);
    k_nodes  <<<2 * NB, 256, 0, stream>>>(srctmp, pairbuf, bbase_src, bcnt_src,
                                          bbase_dst, bcnt_dst, out_norm, in_norm,
                                          indeg, rowstart);
    k_place  <<<NB, 256, 0, stream>>>(pairbuf, rowstart, col);

    // conv1 dense projection (weight_first since 128>32)
    k_gemm1<<<N / 8, 256, 0, stream>>>(in_feat, W1, out_norm, bufA);

    // conv1 aggregate: bufA -> bufB, res = agg*in_norm + b1, pre-scaled by out_norm
    k_spmm<0, 0><<<N / 8, 256, 0, stream>>>(bufA, rowstart, indeg, col, in_norm,
                                            out_norm, W2, b1, bufB);

    // 6 middle convs: ping-pong B->A->B->...
    float* cur = bufB; float* nxt = bufA;
    for (int i = 0; i < 6; ++i) {
        k_spmm<1, 0><<<N / 8, 256, 0, stream>>>(cur, rowstart, indeg, col, in_norm,
                                                out_norm, W2, b2, nxt);
        float* tmp = cur; cur = nxt; nxt = tmp;
    }
    // final conv: cur -> out (no out_norm pre-scale, raw h)
    k_spmm<1, 1><<<N / 8, 256, 0, stream>>>(cur, rowstart, indeg, col, in_norm,
                                            out_norm, W2, b2, out);
}

// Round 11
// 502.247 us; speedup vs baseline: 3.0881x; 1.2219x over previous
//
#include <hip/hip_runtime.h>
#include <hip/hip_bf16.h>

#define NNODES 100000
#define NEDGES 3200000
#define INF 128
#define HID 32
#define NB 392                                 // buckets: node>>8, 256 nodes each
#define BSHIFT 8
#define NPB 256                                // nodes per bucket
#define BATCH 16384                            // edges per partition block
#define PART_BLOCKS ((NEDGES + BATCH - 1) / BATCH)  // 196

typedef unsigned short u16;

__device__ __forceinline__ float blo(unsigned x) { return __uint_as_float(x << 16); }
__device__ __forceinline__ float bhi(unsigned x) { return __uint_as_float(x & 0xffff0000u); }
__device__ __forceinline__ u16 f2b(float f) {
    __hip_bfloat16 h = __float2bfloat16(f);    // RNE
    return *reinterpret_cast<u16*>(&h);
}

// ---- pass 1: per-block LDS bucket histograms -> global bucket counts ----
__global__ void k_cnt(const int* __restrict__ src, const int* __restrict__ dst,
                      int* __restrict__ bcnt_src, int* __restrict__ bcnt_dst) {
    __shared__ int hs[NB], hd[NB];
    int tid = threadIdx.x;
    for (int i = tid; i < NB; i += 1024) { hs[i] = 0; hd[i] = 0; }
    __syncthreads();
    int start = blockIdx.x * BATCH;
    int end = start + BATCH; if (end > NEDGES) end = NEDGES;
    for (int i = start + tid; i < end; i += 1024) {
        atomicAdd(&hs[src[i] >> BSHIFT], 1);
        atomicAdd(&hd[dst[i] >> BSHIFT], 1);
    }
    __syncthreads();
    for (int i = tid; i < NB; i += 1024) {
        if (hs[i]) atomicAdd(&bcnt_src[i], hs[i]);
        if (hd[i]) atomicAdd(&bcnt_dst[i], hd[i]);
    }
}

// ---- pass 2: exclusive scan of the NB-entry bucket counts (both sides) ----
__global__ void k_bscan(const int* __restrict__ bcnt_src, const int* __restrict__ bcnt_dst,
                        int* __restrict__ bbase_src, int* __restrict__ bbase_dst,
                        int* __restrict__ gcur_src, int* __restrict__ gcur_dst) {
    __shared__ int s[512], t[512];
    int tid = threadIdx.x;
    int vs = (tid < NB) ? bcnt_src[tid] : 0;
    int vd = (tid < NB) ? bcnt_dst[tid] : 0;
    s[tid] = vs; t[tid] = vd;
    __syncthreads();
    for (int off = 1; off < 512; off <<= 1) {
        int a = (tid >= off) ? s[tid - off] : 0;
        int b = (tid >= off) ? t[tid - off] : 0;
        __syncthreads();
        s[tid] += a; t[tid] += b;
        __syncthreads();
    }
    if (tid < NB) {
        bbase_src[tid] = s[tid] - vs;  gcur_src[tid] = s[tid] - vs;
        bbase_dst[tid] = t[tid] - vd;  gcur_dst[tid] = t[tid] - vd;
    }
}

// ---- pass 3: partition edges (two passes over 16K-edge batch, LDS cursors) ----
__global__ void k_bucket2(const int* __restrict__ src, const int* __restrict__ dst,
                          int* __restrict__ gcur_src, int* __restrict__ gcur_dst,
                          int2* __restrict__ pairbuf, int* __restrict__ srctmp) {
    __shared__ int cs[NB], cd[NB];
    int tid = threadIdx.x;
    for (int i = tid; i < NB; i += 1024) { cs[i] = 0; cd[i] = 0; }
    __syncthreads();
    int start = blockIdx.x * BATCH;
    int end = start + BATCH; if (end > NEDGES) end = NEDGES;
    for (int i = start + tid; i < end; i += 1024) {
        atomicAdd(&cs[src[i] >> BSHIFT], 1);
        atomicAdd(&cd[dst[i] >> BSHIFT], 1);
    }
    __syncthreads();
    for (int i = tid; i < NB; i += 1024) {
        int c = cs[i];
        cs[i] = c ? atomicAdd(&gcur_src[i], c) : 0;
        c = cd[i];
        cd[i] = c ? atomicAdd(&gcur_dst[i], c) : 0;
    }
    __syncthreads();
    for (int i = start + tid; i < end; i += 1024) {
        int d = dst[i], s = src[i];
        int pd = atomicAdd(&cd[d >> BSHIFT], 1);
        int2 e; e.x = d; e.y = s;
        pairbuf[pd] = e;
        int ps = atomicAdd(&cs[s >> BSHIFT], 1);
        srctmp[ps] = s;
    }
}

// ---- pass 4: per-bucket node stats. b<NB: src-phase (out_norm); else dst-phase
__global__ void k_nodes(const int* __restrict__ srctmp, const int2* __restrict__ pairbuf,
                        const int* __restrict__ bbase_src, const int* __restrict__ bcnt_src,
                        const int* __restrict__ bbase_dst, const int* __restrict__ bcnt_dst,
                        float* __restrict__ out_norm, float* __restrict__ in_norm,
                        int* __restrict__ indeg, int* __restrict__ rowstart) {
    __shared__ int cnt[NPB];
    __shared__ int ss[NPB];
    int tid = threadIdx.x;
    int b = blockIdx.x;
    int srcphase = (b < NB);
    int bb = srcphase ? b : b - NB;
    int node0 = bb * NPB;
    cnt[tid] = 0;
    __syncthreads();
    if (srcphase) {
        int s0 = bbase_src[bb], n = bcnt_src[bb];
        for (int i = tid; i < n; i += 256)
            atomicAdd(&cnt[srctmp[s0 + i] - node0], 1);
        __syncthreads();
        int nn = node0 + tid;
        if (nn < NNODES) {
            int c = cnt[tid];
            out_norm[nn] = rsqrtf((float)(c > 1 ? c : 1));
        }
    } else {
        int d0 = bbase_dst[bb], n = bcnt_dst[bb];
        for (int i = tid; i < n; i += 256)
            atomicAdd(&cnt[pairbuf[d0 + i].x - node0], 1);
        __syncthreads();
        int c = cnt[tid];
        ss[tid] = c;
        __syncthreads();
        for (int off = 1; off < 256; off <<= 1) {
            int t = (tid >= off) ? ss[tid - off] : 0;
            __syncthreads();
            ss[tid] += t;
            __syncthreads();
        }
        int excl = ss[tid] - c;
        int nn = node0 + tid;
        if (nn < NNODES) {
            indeg[nn] = c;
            in_norm[nn] = rsqrtf((float)(c > 1 ? c : 1));
            rowstart[nn] = d0 + excl;
        }
    }
}

// ---- pass 5: within-bucket placement; col window is one bucket (~32KB), L2-local --
__global__ void k_place(const int2* __restrict__ pairbuf, const int* __restrict__ rowstart,
                        int* __restrict__ col) {
    __shared__ int cur[NPB];
    int tid = threadIdx.x;
    int bucket = blockIdx.x;
    int node0 = bucket * NPB;
    if (node0 >= NNODES) return;
    int n = node0 + tid;
    cur[tid] = (n < NNODES) ? rowstart[n] : 0;
    __syncthreads();
    int pstart = rowstart[node0];
    int pend   = (node0 + NPB >= NNODES) ? NEDGES : rowstart[node0 + NPB];
    for (int i = pstart + tid; i < pend; i += 256) {
        int2 e = pairbuf[i];
        int pos = atomicAdd(&cur[e.x - node0], 1);
        col[pos] = e.y;
    }
}

// ---------------- conv1 dense part: t[n] = bf16(out_norm[n] * (x[n] @ W1)) --------
__global__ void k_gemm1(const float* __restrict__ x, const float* __restrict__ W1,
                        const float* __restrict__ out_norm, u16* __restrict__ t) {
    __shared__ float wlds[INF * HID];          // 16 KB
    __shared__ float xlds[8][INF];             // 4 KB
    int tid = threadIdx.x;
    for (int i = tid; i < INF * HID; i += 256) wlds[i] = W1[i];
    int group = tid >> 5, lane = tid & 31;
    int row = blockIdx.x * 8 + group;          // grid = N/8 exact (12500)
    float4 xv = ((const float4*)(x + (size_t)row * INF))[lane];
    ((float4*)xlds[group])[lane] = xv;
    __syncthreads();
    float acc = 0.f;
#pragma unroll
    for (int k = 0; k < INF; ++k)
        acc += xlds[group][k] * wlds[k * HID + lane];
    t[(size_t)row * HID + lane] = f2b(acc * out_norm[row]);
}

// ---------------- fused SpMM step — bf16 features, f32 math -----------------------
// Node row = 32 bf16 = 64B = 4 x uint4. Subgroup g=lane>>2 handles 8 edges/step;
// f=lane&3 picks the 16B quad (features f*8..f*8+7). Halves gather addresses and
// bytes vs f32 (round-10 diagnosis: address-throughput-bound at 8 addrs/edge).
template<int APPLY_W, int FINAL>
__global__ void k_spmm(const u16* __restrict__ gin, const int* __restrict__ rowstart,
                       const int* __restrict__ indeg, const int* __restrict__ col,
                       const float* __restrict__ in_norm, const float* __restrict__ out_norm,
                       const float* __restrict__ W, const float* __restrict__ bias,
                       void* __restrict__ gout) {
    __shared__ float wlds[HID * HID];          // 4 KB
    __shared__ float sh[8][HID];
    int tid = threadIdx.x, lane = tid & 31, group = tid >> 5;
    int g = lane >> 2, f = lane & 3;
    if (APPLY_W) {
        for (int i = tid; i < HID * HID; i += 256) wlds[i] = W[i];
        __syncthreads();
    }
    int n = blockIdx.x * 8 + group;            // grid = N/8 exact
    int start = rowstart[n];
    int deg   = indeg[n];
    const uint4* gin16 = (const uint4*)gin;    // 16B = 8 bf16

    float a[8];
#pragma unroll
    for (int j = 0; j < 8; ++j) a[j] = 0.f;

    int base = 0;
    for (; base + 32 <= deg; base += 32) {     // full chunks: no predication
        int c = col[start + base + lane];
#pragma unroll
        for (int t = 0; t < 4; ++t) {
            int s = __shfl(c, t * 8 + g, 32);
            uint4 v = gin16[(size_t)s * 4 + f];
            a[0] += blo(v.x); a[1] += bhi(v.x);
            a[2] += blo(v.y); a[3] += bhi(v.y);
            a[4] += blo(v.z); a[5] += bhi(v.z);
            a[6] += blo(v.w); a[7] += bhi(v.w);
        }
    }
    if (base < deg) {                          // tail chunk (rem in 1..31)
        int rem = deg - base;
        int c = (base + lane < deg) ? col[start + base + lane] : 0;
#pragma unroll
        for (int t = 0; t < 4; ++t) {
            if (t * 8 < rem) {
                int e = t * 8 + g;
                int s = __shfl(c, e, 32);
                uint4 v = gin16[(size_t)s * 4 + f];
                float m = (e < rem) ? 1.f : 0.f;
                a[0] = fmaf(m, blo(v.x), a[0]); a[1] = fmaf(m, bhi(v.x), a[1]);
                a[2] = fmaf(m, blo(v.y), a[2]); a[3] = fmaf(m, bhi(v.y), a[3]);
                a[4] = fmaf(m, blo(v.z), a[4]); a[5] = fmaf(m, bhi(v.z), a[5]);
                a[6] = fmaf(m, blo(v.w), a[6]); a[7] = fmaf(m, bhi(v.w), a[7]);
            }
        }
    }
    // reduce across the 8 edge-subgroups (lane bits 2,3,4)
#pragma unroll
    for (int j = 0; j < 8; ++j) {
        a[j] += __shfl_xor(a[j], 4, 32);
        a[j] += __shfl_xor(a[j], 8, 32);
        a[j] += __shfl_xor(a[j], 16, 32);
    }
    float inm = in_norm[n];
    if (g == 0) {                              // lanes 0..3 own feature quads
        float4 lo = make_float4(a[0] * inm, a[1] * inm, a[2] * inm, a[3] * inm);
        float4 hi = make_float4(a[4] * inm, a[5] * inm, a[6] * inm, a[7] * inm);
        *(float4*)&sh[group][f * 8]     = lo;  // same-wave LDS fill
        *(float4*)&sh[group][f * 8 + 4] = hi;
    }
    float res;
    if (APPLY_W) {
        float o = bias[lane];
#pragma unroll
        for (int k = 0; k < HID; ++k)
            o += sh[group][k] * wlds[k * HID + lane];
        res = o;
    } else {
        res = sh[group][lane] + bias[lane];
    }
    if (FINAL) ((float*)gout)[(size_t)n * HID + lane] = res;
    else       ((u16*)gout)[(size_t)n * HID + lane] = f2b(res * out_norm[n]);
}

extern "C" void kernel_launch(void* const* d_in, const int* in_sizes, int n_in,
                              void* d_out, int out_size, void* d_ws, size_t ws_size,
                              hipStream_t stream) {
    const float* in_feat = (const float*)d_in[0];
    const float* W1      = (const float*)d_in[1];
    const float* b1      = (const float*)d_in[2];
    const float* W2      = (const float*)d_in[3];
    const float* b2      = (const float*)d_in[4];
    const int*   src     = (const int*)d_in[5];
    const int*   dst     = (const int*)d_in[6];
    float*       out     = (float*)d_out;

    const int N = NNODES, E = NEDGES;
    // workspace layout (4-byte units)
    int* bcnt_src  = (int*)d_ws;                // 512
    int* bcnt_dst  = bcnt_src + 512;            // 512
    int* bbase_src = bcnt_dst + 512;            // 512
    int* bbase_dst = bbase_src + 512;           // 512
    int* gcur_src  = bbase_dst + 512;           // 512
    int* gcur_dst  = gcur_src + 512;            // 512
    int* indeg     = gcur_dst + 512;            // N
    int* rowstart  = indeg + N;                 // N
    float* out_norm = (float*)(rowstart + N);   // N
    float* in_norm  = out_norm + N;             // N
    int*   col      = (int*)(in_norm + N);      // E   (aliased as srctmp pre-place)
    void*  bufreg   = (void*)(col + E);         // E int2 region (pairbuf), later bf16 bufs
    int2*  pairbuf  = (int2*)bufreg;            // E pairs
    int*   srctmp   = col;                      // E ints, consumed before col written
    u16*   bufA16   = (u16*)bufreg;             // N*HID bf16 (6.4MB, fits in pairbuf region)
    u16*   bufB16   = bufA16 + (size_t)N * HID; // N*HID bf16
    size_t need = ((size_t)3072 + 4 * N + E + (size_t)2 * N * HID) * 4;
    if (ws_size < need) return;                 // fail visibly rather than corrupt

    hipMemsetAsync(bcnt_src, 0, 1024 * sizeof(int), stream);  // bcnt_src + bcnt_dst

    k_cnt    <<<PART_BLOCKS, 1024, 0, stream>>>(src, dst, bcnt_src, bcnt_dst);
    k_bscan  <<<1, 512, 0, stream>>>(bcnt_src, bcnt_dst, bbase_src, bbase_dst,
                                     gcur_src, gcur_dst);
    k_bucket2<<<PART_BLOCKS, 1024, 0, stream>>>(src, dst, gcur_src, gcur_dst,
                                                pairbuf, srctmp);
    k_nodes  <<<2 * NB, 256, 0, stream>>>(srctmp, pairbuf, bbase_src, bcnt_src,
                                          bbase_dst, bcnt_dst, out_norm, in_norm,
                                          indeg, rowstart);
    k_place  <<<NB, 256, 0, stream>>>(pairbuf, rowstart, col);

    // conv1 dense projection (weight_first since 128>32), bf16 output
    k_gemm1<<<N / 8, 256, 0, stream>>>(in_feat, W1, out_norm, bufA16);

    // conv1 aggregate: bufA -> bufB, res = agg*in_norm + b1, pre-scaled by out_norm
    k_spmm<0, 0><<<N / 8, 256, 0, stream>>>(bufA16, rowstart, indeg, col, in_norm,
                                            out_norm, W2, b1, bufB16);

    // 6 middle convs: ping-pong B->A->B->...
    u16* cur = bufB16; u16* nxt = bufA16;
    for (int i = 0; i < 6; ++i) {
        k_spmm<1, 0><<<N / 8, 256, 0, stream>>>(cur, rowstart, indeg, col, in_norm,
                                                out_norm, W2, b2, nxt);
        u16* tmp = cur; cur = nxt; nxt = tmp;
    }
    // final conv: cur -> out (f32, no out_norm pre-scale)
    k_spmm<1, 1><<<N / 8, 256, 0, stream>>>(cur, rowstart, indeg, col, in_norm,
                                            out_norm, W2, b2, out);
}